// Round 1
// baseline (11846.487 us; speedup 1.0000x reference)
//
#include <hip/hip_runtime.h>
#include <math.h>

#define L_LEN 4096
#define DEV __device__ __forceinline__

DEV float silu_f(float x) { return x / (1.f + expf(-x)); }
DEV float sigm_f(float x) { return 1.f / (1.f + expf(-x)); }

// MODE 0: out = silu(bn(conv))
// MODE 1: out = aux * sigmoid(bn(conv))        (attention gate, in-place safe: aux==out)
// MODE 3: h = silu(bn(conv) + aux); atomically accumulate sum over l into gsum[b*COUT+co]
template <int K, int DIL, int MODE, int CIN, int COUT, int T>
__launch_bounds__(256) __global__
void conv_bn_k(const float* __restrict__ in, const float* __restrict__ W,
               const float* __restrict__ bias, const float* __restrict__ bnp,
               const float* __restrict__ aux, float* __restrict__ out,
               float* __restrict__ gsum)
{
    constexpr int PAD = (K - 1) * DIL / 2;
    constexpr int WIN = T + (K - 1) * DIL;
    constexpr int WPC = CIN * K;

    __shared__ float wsh_all[4 * WPC];

    const int tx = threadIdx.x & 63;
    const int ty = threadIdx.x >> 6;          // 0..3 -> co within block
    const int co = (blockIdx.y << 2) + ty;
    const int b  = blockIdx.z;
    const int l0 = blockIdx.x * (64 * T) + tx * T;

    // stage this block's 4 output-channels' weights in LDS
    for (int i = threadIdx.x; i < 4 * WPC; i += 256)
        wsh_all[i] = W[(size_t)(blockIdx.y * 4) * WPC + i];
    __syncthreads();
    const float* wsh = wsh_all + ty * WPC;

    float acc[T];
#pragma unroll
    for (int t = 0; t < T; ++t) acc[t] = 0.f;

    const float* inb  = in + (size_t)b * CIN * L_LEN;
    const int    base = l0 - PAD;

    if (base >= 0 && base + WIN <= L_LEN) {
#pragma unroll 2
        for (int ci = 0; ci < CIN; ++ci) {
            const float* ip = inb + ci * L_LEN + base;
            float win[WIN];
#pragma unroll
            for (int j = 0; j < WIN; ++j) win[j] = ip[j];
#pragma unroll
            for (int k = 0; k < K; ++k) {
                const float wv = wsh[ci * K + k];
#pragma unroll
                for (int t = 0; t < T; ++t) acc[t] = fmaf(wv, win[k * DIL + t], acc[t]);
            }
        }
    } else {
        for (int ci = 0; ci < CIN; ++ci) {
            const float* ip = inb + ci * L_LEN;
            float win[WIN];
#pragma unroll
            for (int j = 0; j < WIN; ++j) {
                const int ix = base + j;
                win[j] = (ix >= 0 && ix < L_LEN) ? ip[ix] : 0.f;
            }
#pragma unroll
            for (int k = 0; k < K; ++k) {
                const float wv = wsh[ci * K + k];
#pragma unroll
                for (int t = 0; t < T; ++t) acc[t] = fmaf(wv, win[k * DIL + t], acc[t]);
            }
        }
    }

    // folded BN: z = conv*sc + sh, with conv-bias folded in
    const float gm = bnp[co], bt = bnp[COUT + co], mn = bnp[2 * COUT + co], vr = bnp[3 * COUT + co];
    const float sc = gm / sqrtf(vr + 1e-5f);
    const float sh = (bias[co] - mn) * sc + bt;
    const size_t ob = ((size_t)b * COUT + co) * L_LEN + l0;

    if constexpr (MODE == 0) {
#pragma unroll
        for (int t = 0; t < T; ++t) {
            float z = fmaf(acc[t], sc, sh);
            out[ob + t] = silu_f(z);
        }
    } else if constexpr (MODE == 1) {
#pragma unroll
        for (int t = 0; t < T; ++t) {
            float z = fmaf(acc[t], sc, sh);
            out[ob + t] = aux[ob + t] * sigm_f(z);
        }
    } else {  // MODE 3
        float s = 0.f;
#pragma unroll
        for (int t = 0; t < T; ++t) {
            float z = fmaf(acc[t], sc, sh) + aux[ob + t];
            s += silu_f(z);
        }
        // all 64 lanes of a wave share the same co (ty constant per wave)
#pragma unroll
        for (int off = 32; off >= 1; off >>= 1) s += __shfl_down(s, off, 64);
        if (tx == 0) atomicAdd(&gsum[b * COUT + co], s);
    }
}

// ---------------- 4-qubit statevector circuit, one thread per batch row ----------------
template <int BW> DEV void g_ry(float (&re)[16], float (&im)[16], float t) {
    float s, c; sincosf(0.5f * t, &s, &c);
#pragma unroll
    for (int i = 0; i < 16; ++i)
        if (!(i & BW)) {
            const int j = i | BW;
            float r0 = re[i], q0 = im[i], r1 = re[j], q1 = im[j];
            re[i] = c * r0 - s * r1; im[i] = c * q0 - s * q1;
            re[j] = s * r0 + c * r1; im[j] = s * q0 + c * q1;
        }
}
template <int BW> DEV void g_rz(float (&re)[16], float (&im)[16], float t) {
    float s, c; sincosf(0.5f * t, &s, &c);
#pragma unroll
    for (int i = 0; i < 16; ++i) {
        float r = re[i], q = im[i];
        if (i & BW) { re[i] = r * c - q * s; im[i] = q * c + r * s; }   // e^{+i t/2}
        else        { re[i] = r * c + q * s; im[i] = q * c - r * s; }   // e^{-i t/2}
    }
}
template <int BC, int BT> DEV void g_cnot(float (&re)[16], float (&im)[16]) {
#pragma unroll
    for (int i = 0; i < 16; ++i)
        if ((i & BC) && !(i & BT)) {
            const int j = i | BT;
            float r = re[i]; re[i] = re[j]; re[j] = r;
            float q = im[i]; im[i] = im[j]; im[j] = q;
        }
}

__global__ void quantum_k(const float* __restrict__ gsum, const float* __restrict__ Wfm,
                          const float* __restrict__ bfm, const float* __restrict__ qw,
                          float* __restrict__ q, int B)
{
    const int b = blockIdx.x * blockDim.x + threadIdx.x;
    if (b >= B) return;

    // qin = mean(h2 over L) @ Wfm.T + bfm
    float qin[4];
#pragma unroll
    for (int j = 0; j < 4; ++j) qin[j] = bfm[j];
    const float inv = 1.f / (float)L_LEN;
    for (int c = 0; c < 128; ++c) {
        const float gv = gsum[b * 128 + c] * inv;
#pragma unroll
        for (int j = 0; j < 4; ++j) qin[j] = fmaf(gv, Wfm[j * 128 + c], qin[j]);
    }

    float re[16], im[16];
#pragma unroll
    for (int i = 0; i < 16; ++i) { re[i] = 0.f; im[i] = 0.f; }
    re[0] = 1.f;

    g_ry<8>(re, im, qin[0]); g_ry<4>(re, im, qin[1]); g_ry<2>(re, im, qin[2]); g_ry<1>(re, im, qin[3]);
    g_rz<8>(re, im, qw[0]);  g_ry<8>(re, im, qw[1]);
    g_rz<4>(re, im, qw[2]);  g_ry<4>(re, im, qw[3]);
    g_rz<2>(re, im, qw[4]);  g_ry<2>(re, im, qw[5]);
    g_rz<1>(re, im, qw[6]);  g_ry<1>(re, im, qw[7]);
    g_cnot<8, 4>(re, im); g_cnot<4, 2>(re, im); g_cnot<2, 1>(re, im);
    g_rz<8>(re, im, qw[8]);  g_ry<8>(re, im, qw[9]);
    g_rz<4>(re, im, qw[10]); g_ry<4>(re, im, qw[11]);
    g_rz<2>(re, im, qw[12]); g_ry<2>(re, im, qw[13]);
    g_rz<1>(re, im, qw[14]); g_ry<1>(re, im, qw[15]);

    float p[16];
#pragma unroll
    for (int i = 0; i < 16; ++i) p[i] = re[i] * re[i] + im[i] * im[i];
#pragma unroll
    for (int w = 0; w < 4; ++w) {
        const int bw = 8 >> w;
        float e = 0.f;
#pragma unroll
        for (int i = 0; i < 16; ++i) e += (i & bw) ? -p[i] : p[i];
        q[b * 4 + w] = e;
    }
}

// ---------------- FC head: 4 -> 64 -> 32 -> 1, one block (64 thr) per row ----------------
__global__ void head_k(const float* __restrict__ q,
                       const float* __restrict__ Wf1, const float* __restrict__ bf1, const float* __restrict__ bnf1,
                       const float* __restrict__ Wf2, const float* __restrict__ bf2, const float* __restrict__ bnf2,
                       const float* __restrict__ Wf3, const float* __restrict__ bf3,
                       float* __restrict__ out)
{
    const int b = blockIdx.x, t = threadIdx.x;
    __shared__ float qs[4], x1[64], x2[32];
    if (t < 4) qs[t] = q[b * 4 + t];
    __syncthreads();
    {
        float a = bf1[t];
#pragma unroll
        for (int k = 0; k < 4; ++k) a = fmaf(qs[k], Wf1[t * 4 + k], a);
        const float sc = bnf1[t] / sqrtf(bnf1[192 + t] + 1e-5f);
        const float z  = (a - bnf1[128 + t]) * sc + bnf1[64 + t];
        x1[t] = silu_f(z);
    }
    __syncthreads();
    if (t < 32) {
        float a = bf2[t];
        for (int k = 0; k < 64; ++k) a = fmaf(x1[k], Wf2[t * 64 + k], a);
        const float sc = bnf2[t] / sqrtf(bnf2[96 + t] + 1e-5f);
        const float z  = (a - bnf2[64 + t]) * sc + bnf2[32 + t];
        x2[t] = silu_f(z);
    }
    __syncthreads();
    if (t == 0) {
        float a = bf3[0];
        for (int k = 0; k < 32; ++k) a = fmaf(x2[k], Wf3[k], a);
        out[b] = a;
    }
}

extern "C" void kernel_launch(void* const* d_in, const int* in_sizes, int n_in,
                              void* d_out, int out_size, void* d_ws, size_t ws_size,
                              hipStream_t stream)
{
    (void)n_in; (void)out_size;
    const float* x    = (const float*)d_in[0];
    const float* W1   = (const float*)d_in[1];
    const float* b1   = (const float*)d_in[2];
    const float* bn1  = (const float*)d_in[3];
    const float* Wa1  = (const float*)d_in[4];
    const float* ba1  = (const float*)d_in[5];
    const float* bna1 = (const float*)d_in[6];
    const float* Wa2  = (const float*)d_in[7];
    const float* ba2  = (const float*)d_in[8];
    const float* bna2 = (const float*)d_in[9];
    const float* Wd1  = (const float*)d_in[10];
    const float* bdd1 = (const float*)d_in[11];
    const float* bnd1 = (const float*)d_in[12];
    const float* Wd2  = (const float*)d_in[13];
    const float* bdd2 = (const float*)d_in[14];
    const float* bnd2 = (const float*)d_in[15];
    const float* Wr1  = (const float*)d_in[16];
    const float* br1  = (const float*)d_in[17];
    const float* bnr1 = (const float*)d_in[18];
    const float* Wr2  = (const float*)d_in[19];
    const float* br2  = (const float*)d_in[20];
    const float* bnr2 = (const float*)d_in[21];
    const float* Wfm  = (const float*)d_in[22];
    const float* bfm  = (const float*)d_in[23];
    const float* qw   = (const float*)d_in[24];
    const float* Wf1  = (const float*)d_in[25];
    const float* bf1  = (const float*)d_in[26];
    const float* bnf1 = (const float*)d_in[27];
    const float* Wf2  = (const float*)d_in[28];
    const float* bf2  = (const float*)d_in[29];
    const float* bnf2 = (const float*)d_in[30];
    const float* Wf3  = (const float*)d_in[31];
    const float* bf3  = (const float*)d_in[32];

    const int B = in_sizes[0] / L_LEN;  // 128

    // ---- workspace layout (floats) ----
    float* ws   = (float*)d_ws;
    float* gbuf = ws;                          // [B,128] pooled sums
    float* qbuf = gbuf + (size_t)B * 128;      // [B,4]
    float* big  = qbuf + (size_t)B * 4;
    const size_t small_f = (size_t)B * 132;
    const size_t PS      = (size_t)(64 + 32 + 128 + 128) * L_LEN;  // floats per sample
    const size_t avail_f = (ws_size / 4 > small_f) ? (ws_size / 4 - small_f) : 0;
    int chunk = B;
    while (chunk > 1 && (size_t)chunk * PS > avail_f) chunk >>= 1;

    float* h0  = big;                                  // [chunk,64,L] (becomes h1 in-place)
    float* a1b = h0  + (size_t)chunk * 64  * L_LEN;    // [chunk,32,L]
    float* d1b = a1b + (size_t)chunk * 32  * L_LEN;    // [chunk,128,L] (reused for r1)
    float* d2b = d1b + (size_t)chunk * 128 * L_LEN;    // [chunk,128,L]

    hipMemsetAsync(gbuf, 0, (size_t)B * 128 * sizeof(float), stream);

    constexpr int T = 8;
    const dim3 blk(256);
    const int LB = L_LEN / (64 * T);  // 8 l-blocks

    for (int s = 0; s < B; s += chunk) {
        const float* xin = x + (size_t)s * L_LEN;
        conv_bn_k<5, 1, 0, 1,   64,  T><<<dim3(LB, 16, chunk), blk, 0, stream>>>(xin, W1,  b1,   bn1,  nullptr, h0,  nullptr);
        conv_bn_k<7, 1, 0, 64,  32,  T><<<dim3(LB, 8,  chunk), blk, 0, stream>>>(h0,  Wa1, ba1,  bna1, nullptr, a1b, nullptr);
        conv_bn_k<7, 1, 1, 32,  64,  T><<<dim3(LB, 16, chunk), blk, 0, stream>>>(a1b, Wa2, ba2,  bna2, h0,      h0,  nullptr);
        conv_bn_k<3, 2, 0, 64,  128, T><<<dim3(LB, 32, chunk), blk, 0, stream>>>(h0,  Wd1, bdd1, bnd1, nullptr, d1b, nullptr);
        conv_bn_k<3, 4, 0, 128, 128, T><<<dim3(LB, 32, chunk), blk, 0, stream>>>(d1b, Wd2, bdd2, bnd2, nullptr, d2b, nullptr);
        conv_bn_k<3, 1, 0, 128, 128, T><<<dim3(LB, 32, chunk), blk, 0, stream>>>(d2b, Wr1, br1,  bnr1, nullptr, d1b, nullptr);
        conv_bn_k<3, 1, 3, 128, 128, T><<<dim3(LB, 32, chunk), blk, 0, stream>>>(d1b, Wr2, br2,  bnr2, d2b,     nullptr, gbuf + (size_t)s * 128);
    }

    quantum_k<<<dim3((B + 127) / 128), dim3(128), 0, stream>>>(gbuf, Wfm, bfm, qw, qbuf, B);
    head_k<<<dim3(B), dim3(64), 0, stream>>>(qbuf, Wf1, bf1, bnf1, Wf2, bf2, bnf2, Wf3, bf3, (float*)d_out);
}

// Round 2
// 1407.683 us; speedup vs baseline: 8.4156x; 8.4156x over previous
//
#include <hip/hip_runtime.h>
#include <math.h>

#define L_LEN 4096
#define DEV __device__ __forceinline__

typedef __attribute__((ext_vector_type(8))) __bf16 bf16x8;
typedef __attribute__((ext_vector_type(4))) float  f32x4;

DEV float silu_f(float x) { return x / (1.f + expf(-x)); }
DEV float sigm_f(float x) { return 1.f / (1.f + expf(-x)); }

// ============================================================================
// conv1: CIN=1, K=5, pad=2  (fp32 direct; writes split hi/lo bf16 channels-last)
// grid (L/64, B), block 256. thread: l = blockIdx.x*64 + t/4, co-quad = (t&3)*16
// ============================================================================
__global__ __launch_bounds__(256) void conv1_split_k(
    const float* __restrict__ x, const float* __restrict__ W,
    const float* __restrict__ bias, const float* __restrict__ bnp,
    __bf16* __restrict__ outhi, __bf16* __restrict__ outlo)
{
    __shared__ float sw[64 * 5];
    __shared__ float ssc[64], ssh[64];
    const int tid = threadIdx.x;
    if (tid < 64) {
        float g = bnp[tid], be = bnp[64 + tid], mn = bnp[128 + tid], vr = bnp[192 + tid];
        float sc = g * rsqrtf(vr + 1e-5f);
        ssc[tid] = sc;
        ssh[tid] = fmaf(bias[tid] - mn, sc, be);
    }
    for (int i = tid; i < 320; i += 256) sw[i] = W[i];
    __syncthreads();

    const int b = blockIdx.y;
    const int l = blockIdx.x * 64 + (tid >> 2);
    const int cq = (tid & 3) * 16;

    float win[5];
#pragma unroll
    for (int k = 0; k < 5; ++k) {
        int ix = l + k - 2;
        win[k] = (ix >= 0 && ix < L_LEN) ? x[(size_t)b * L_LEN + ix] : 0.f;
    }
    __align__(16) __bf16 vh[16];
    __align__(16) __bf16 vl[16];
#pragma unroll
    for (int j = 0; j < 16; ++j) {
        const int co = cq + j;
        float z = 0.f;
#pragma unroll
        for (int k = 0; k < 5; ++k) z = fmaf(sw[co * 5 + k], win[k], z);
        z = fmaf(z, ssc[co], ssh[co]);
        float v = silu_f(z);
        __bf16 h = (__bf16)v;
        vh[j] = h;
        vl[j] = (__bf16)(v - (float)h);
    }
    const size_t o = ((size_t)b * L_LEN + l) * 64 + cq;
    *(int4*)(outhi + o)     = *(const int4*)(vh);
    *(int4*)(outhi + o + 8) = *(const int4*)(vh + 8);
    *(int4*)(outlo + o)     = *(const int4*)(vl);
    *(int4*)(outlo + o + 8) = *(const int4*)(vl + 8);
}

// ============================================================================
// weight prep: W[co][ci][k] fp32 -> Wt[k][co][ci] split bf16 hi/lo
// ============================================================================
template <int CIN, int COUT, int K>
__global__ void prep_w_k(const float* __restrict__ W, __bf16* __restrict__ whi,
                         __bf16* __restrict__ wlo)
{
    const int i = blockIdx.x * 256 + threadIdx.x;
    if (i >= K * COUT * CIN) return;
    const int ci = i % CIN;
    const int co = (i / CIN) % COUT;
    const int k  = i / (CIN * COUT);
    const float v = W[(co * CIN + ci) * K + k];
    __bf16 h = (__bf16)v;
    whi[i] = h;
    wlo[i] = (__bf16)(v - (float)h);
}

// ============================================================================
// MFMA split-bf16 implicit-GEMM conv.
// Activations channels-last: plane[b][l][C], hi & lo separate planes.
// Block: 256 thr = 4 waves (2 wl x 2 wc); block tile = 128 l x COUT co.
// Wave: 4 m-tiles (64 l) x NT n-tiles (NT = COUT/32).
// K-loop: ci-slices of 32; per slice stage input window + weight slab in LDS.
// MODE 0: silu -> split store
// MODE 1: out = aux * sigmoid(z) -> split store      (aux = gate input, C==COUT)
// MODE 3: v = silu(z + aux); pool-sum over l -> atomicAdd gsum[b*COUT+co]
// ============================================================================
template <int CIN, int COUT, int K, int DIL, int MODE>
__launch_bounds__(256, 2) __global__ void conv_mfma_k(
    const __bf16* __restrict__ inhi, const __bf16* __restrict__ inlo,
    const __bf16* __restrict__ whi,  const __bf16* __restrict__ wlo,
    const float* __restrict__ bias,  const float* __restrict__ bnp,
    const __bf16* __restrict__ auxhi, const __bf16* __restrict__ auxlo,
    __bf16* __restrict__ outhi, __bf16* __restrict__ outlo,
    float* __restrict__ gsum)
{
    constexpr int PADR = ((K - 1) / 2) * DIL;
    constexpr int LWIN = 128 + (K - 1) * DIL;
    constexpr int NT   = COUT / 32;          // n-tiles per wave (wave covers COUT/2)
    constexpr int SL   = CIN / 32;           // ci slices

    __shared__ __align__(16) __bf16 sIn[2][LWIN][32];
    __shared__ __align__(16) __bf16 sW[2][K][COUT][32];

    const int tid  = threadIdx.x;
    const int lane = tid & 63;
    const int w    = tid >> 6;
    const int wl   = w >> 1;                 // 0..1 : l half
    const int wc   = w & 1;                  // 0..1 : co half
    const int b    = blockIdx.z;
    const int l0   = blockIdx.x * 128;
    const int lan15 = lane & 15;
    const int kg    = (lane >> 4) * 8;       // ci_local start for frags

    f32x4 acc[4][NT];
#pragma unroll
    for (int mt = 0; mt < 4; ++mt)
#pragma unroll
        for (int nt = 0; nt < NT; ++nt) acc[mt][nt] = (f32x4){0.f, 0.f, 0.f, 0.f};

    for (int s = 0; s < SL; ++s) {
        const int ci0 = s * 32;
        __syncthreads();   // protect previous slice's LDS reads
        // ---- stage input window (hi+lo), rows = 64B, conflict-free ----
#pragma unroll
        for (int i = tid; i < LWIN * 4 * 2; i += 256) {
            const int pl  = (i >= LWIN * 4) ? 1 : 0;
            const int j   = pl ? i - LWIN * 4 : i;
            const int row = j >> 2, slot = j & 3;
            const int gl  = l0 - PADR + row;
            int4 v = {0, 0, 0, 0};
            if (gl >= 0 && gl < L_LEN) {
                const __bf16* src = (pl ? inlo : inhi) +
                    (((size_t)b * L_LEN + gl) * CIN + ci0 + slot * 8);
                v = *(const int4*)src;
            }
            *(int4*)((__bf16*)sIn[pl] + (size_t)j * 8) = v;
        }
        // ---- stage weight slab [K][COUT][32] hi+lo ----
#pragma unroll
        for (int i = tid; i < K * COUT * 4 * 2; i += 256) {
            const int pl  = (i >= K * COUT * 4) ? 1 : 0;
            const int j   = pl ? i - K * COUT * 4 : i;      // j = (k*COUT+co)*4 + slot
            const int row = j >> 2, slot = j & 3;
            const __bf16* src = (pl ? wlo : whi) + ((size_t)row * CIN + ci0 + slot * 8);
            *(int4*)((__bf16*)sW[pl] + (size_t)j * 8) = *(const int4*)src;
        }
        __syncthreads();

#pragma unroll
        for (int tap = 0; tap < K; ++tap) {
            // preload B (weight) frags for this tap
            bf16x8 bh[NT], bl[NT];
#pragma unroll
            for (int nt = 0; nt < NT; ++nt) {
                const int co = wc * (COUT / 2) + nt * 16 + lan15;
                bh[nt] = *(const bf16x8*)&sW[0][tap][co][kg];
                bl[nt] = *(const bf16x8*)&sW[1][tap][co][kg];
            }
#pragma unroll
            for (int mt = 0; mt < 4; ++mt) {
                const int row = wl * 64 + mt * 16 + lan15 + tap * DIL;
                const bf16x8 ah = *(const bf16x8*)&sIn[0][row][kg];
                const bf16x8 al = *(const bf16x8*)&sIn[1][row][kg];
#pragma unroll
                for (int nt = 0; nt < NT; ++nt) {
                    acc[mt][nt] = __builtin_amdgcn_mfma_f32_16x16x32_bf16(ah, bh[nt], acc[mt][nt], 0, 0, 0);
                    acc[mt][nt] = __builtin_amdgcn_mfma_f32_16x16x32_bf16(ah, bl[nt], acc[mt][nt], 0, 0, 0);
                    acc[mt][nt] = __builtin_amdgcn_mfma_f32_16x16x32_bf16(al, bh[nt], acc[mt][nt], 0, 0, 0);
                }
            }
        }
    }

    // ---- epilogue ----
#pragma unroll
    for (int nt = 0; nt < NT; ++nt) {
        const int co = wc * (COUT / 2) + nt * 16 + lan15;
        const float g = bnp[co], be = bnp[COUT + co], mn = bnp[2 * COUT + co], vr = bnp[3 * COUT + co];
        const float sc = g * rsqrtf(vr + 1e-5f);
        const float sh = fmaf(bias[co] - mn, sc, be);
        float ps = 0.f;
#pragma unroll
        for (int mt = 0; mt < 4; ++mt) {
#pragma unroll
            for (int r = 0; r < 4; ++r) {
                const int l = l0 + wl * 64 + mt * 16 + (lane >> 4) * 4 + r;
                const size_t gidx = ((size_t)b * L_LEN + l) * COUT + co;
                const float z = fmaf(acc[mt][nt][r], sc, sh);
                if constexpr (MODE == 0) {
                    const float v = silu_f(z);
                    const __bf16 hb = (__bf16)v;
                    outhi[gidx] = hb;
                    outlo[gidx] = (__bf16)(v - (float)hb);
                } else if constexpr (MODE == 1) {
                    const float gate = (float)auxhi[gidx] + (float)auxlo[gidx];
                    const float v = gate * sigm_f(z);
                    const __bf16 hb = (__bf16)v;
                    outhi[gidx] = hb;
                    outlo[gidx] = (__bf16)(v - (float)hb);
                } else {
                    const float res = (float)auxhi[gidx] + (float)auxlo[gidx];
                    ps += silu_f(z + res);
                }
            }
        }
        if constexpr (MODE == 3) {
            ps += __shfl_down(ps, 32, 64);
            ps += __shfl_down(ps, 16, 64);
            if ((lane >> 4) == 0) atomicAdd(&gsum[b * COUT + co], ps);
        }
    }
}

// ============================================================================
// 4-qubit statevector circuit, one thread per batch row
// ============================================================================
template <int BW> DEV void g_ry(float (&re)[16], float (&im)[16], float t) {
    float s, c; sincosf(0.5f * t, &s, &c);
#pragma unroll
    for (int i = 0; i < 16; ++i)
        if (!(i & BW)) {
            const int j = i | BW;
            float r0 = re[i], q0 = im[i], r1 = re[j], q1 = im[j];
            re[i] = c * r0 - s * r1; im[i] = c * q0 - s * q1;
            re[j] = s * r0 + c * r1; im[j] = s * q0 + c * q1;
        }
}
template <int BW> DEV void g_rz(float (&re)[16], float (&im)[16], float t) {
    float s, c; sincosf(0.5f * t, &s, &c);
#pragma unroll
    for (int i = 0; i < 16; ++i) {
        float r = re[i], q = im[i];
        if (i & BW) { re[i] = r * c - q * s; im[i] = q * c + r * s; }
        else        { re[i] = r * c + q * s; im[i] = q * c - r * s; }
    }
}
template <int BC, int BT> DEV void g_cnot(float (&re)[16], float (&im)[16]) {
#pragma unroll
    for (int i = 0; i < 16; ++i)
        if ((i & BC) && !(i & BT)) {
            const int j = i | BT;
            float r = re[i]; re[i] = re[j]; re[j] = r;
            float q = im[i]; im[i] = im[j]; im[j] = q;
        }
}

__global__ void quantum_k(const float* __restrict__ gsum, const float* __restrict__ Wfm,
                          const float* __restrict__ bfm, const float* __restrict__ qw,
                          float* __restrict__ q, int B)
{
    const int b = blockIdx.x * blockDim.x + threadIdx.x;
    if (b >= B) return;

    float qin[4];
#pragma unroll
    for (int j = 0; j < 4; ++j) qin[j] = bfm[j];
    const float inv = 1.f / (float)L_LEN;
    for (int c = 0; c < 128; ++c) {
        const float gv = gsum[b * 128 + c] * inv;
#pragma unroll
        for (int j = 0; j < 4; ++j) qin[j] = fmaf(gv, Wfm[j * 128 + c], qin[j]);
    }

    float re[16], im[16];
#pragma unroll
    for (int i = 0; i < 16; ++i) { re[i] = 0.f; im[i] = 0.f; }
    re[0] = 1.f;

    g_ry<8>(re, im, qin[0]); g_ry<4>(re, im, qin[1]); g_ry<2>(re, im, qin[2]); g_ry<1>(re, im, qin[3]);
    g_rz<8>(re, im, qw[0]);  g_ry<8>(re, im, qw[1]);
    g_rz<4>(re, im, qw[2]);  g_ry<4>(re, im, qw[3]);
    g_rz<2>(re, im, qw[4]);  g_ry<2>(re, im, qw[5]);
    g_rz<1>(re, im, qw[6]);  g_ry<1>(re, im, qw[7]);
    g_cnot<8, 4>(re, im); g_cnot<4, 2>(re, im); g_cnot<2, 1>(re, im);
    g_rz<8>(re, im, qw[8]);  g_ry<8>(re, im, qw[9]);
    g_rz<4>(re, im, qw[10]); g_ry<4>(re, im, qw[11]);
    g_rz<2>(re, im, qw[12]); g_ry<2>(re, im, qw[13]);
    g_rz<1>(re, im, qw[14]); g_ry<1>(re, im, qw[15]);

    float p[16];
#pragma unroll
    for (int i = 0; i < 16; ++i) p[i] = re[i] * re[i] + im[i] * im[i];
#pragma unroll
    for (int w = 0; w < 4; ++w) {
        const int bw = 8 >> w;
        float e = 0.f;
#pragma unroll
        for (int i = 0; i < 16; ++i) e += (i & bw) ? -p[i] : p[i];
        q[b * 4 + w] = e;
    }
}

// ============================================================================
// FC head: 4 -> 64 -> 32 -> 1
// ============================================================================
__global__ void head_k(const float* __restrict__ q,
                       const float* __restrict__ Wf1, const float* __restrict__ bf1, const float* __restrict__ bnf1,
                       const float* __restrict__ Wf2, const float* __restrict__ bf2, const float* __restrict__ bnf2,
                       const float* __restrict__ Wf3, const float* __restrict__ bf3,
                       float* __restrict__ out)
{
    const int b = blockIdx.x, t = threadIdx.x;
    __shared__ float qs[4], x1[64], x2[32];
    if (t < 4) qs[t] = q[b * 4 + t];
    __syncthreads();
    {
        float a = bf1[t];
#pragma unroll
        for (int k = 0; k < 4; ++k) a = fmaf(qs[k], Wf1[t * 4 + k], a);
        const float sc = bnf1[t] / sqrtf(bnf1[192 + t] + 1e-5f);
        const float z  = (a - bnf1[128 + t]) * sc + bnf1[64 + t];
        x1[t] = silu_f(z);
    }
    __syncthreads();
    if (t < 32) {
        float a = bf2[t];
        for (int k = 0; k < 64; ++k) a = fmaf(x1[k], Wf2[t * 64 + k], a);
        const float sc = bnf2[t] / sqrtf(bnf2[96 + t] + 1e-5f);
        const float z  = (a - bnf2[64 + t]) * sc + bnf2[32 + t];
        x2[t] = silu_f(z);
    }
    __syncthreads();
    if (t == 0) {
        float a = bf3[0];
        for (int k = 0; k < 32; ++k) a = fmaf(x2[k], Wf3[k], a);
        out[b] = a;
    }
}

// ============================================================================
extern "C" void kernel_launch(void* const* d_in, const int* in_sizes, int n_in,
                              void* d_out, int out_size, void* d_ws, size_t ws_size,
                              hipStream_t stream)
{
    (void)n_in; (void)out_size;
    const float* x    = (const float*)d_in[0];
    const float* W1   = (const float*)d_in[1];
    const float* b1   = (const float*)d_in[2];
    const float* bn1  = (const float*)d_in[3];
    const float* Wa1  = (const float*)d_in[4];
    const float* ba1  = (const float*)d_in[5];
    const float* bna1 = (const float*)d_in[6];
    const float* Wa2  = (const float*)d_in[7];
    const float* ba2  = (const float*)d_in[8];
    const float* bna2 = (const float*)d_in[9];
    const float* Wd1  = (const float*)d_in[10];
    const float* bdd1 = (const float*)d_in[11];
    const float* bnd1 = (const float*)d_in[12];
    const float* Wd2  = (const float*)d_in[13];
    const float* bdd2 = (const float*)d_in[14];
    const float* bnd2 = (const float*)d_in[15];
    const float* Wr1  = (const float*)d_in[16];
    const float* br1  = (const float*)d_in[17];
    const float* bnr1 = (const float*)d_in[18];
    const float* Wr2  = (const float*)d_in[19];
    const float* br2  = (const float*)d_in[20];
    const float* bnr2 = (const float*)d_in[21];
    const float* Wfm  = (const float*)d_in[22];
    const float* bfm  = (const float*)d_in[23];
    const float* qw   = (const float*)d_in[24];
    const float* Wf1  = (const float*)d_in[25];
    const float* bf1  = (const float*)d_in[26];
    const float* bnf1 = (const float*)d_in[27];
    const float* Wf2  = (const float*)d_in[28];
    const float* bf2  = (const float*)d_in[29];
    const float* bnf2 = (const float*)d_in[30];
    const float* Wf3  = (const float*)d_in[31];
    const float* bf3  = (const float*)d_in[32];

    const int B = in_sizes[0] / L_LEN;  // 128

    // ---- workspace carve (256B aligned bump allocator) ----
    char* base = (char*)d_ws;
    size_t off = 0;
    auto alloc = [&](size_t bytes) -> char* {
        off = (off + 255) & ~(size_t)255;
        char* p = base + off;
        off += bytes;
        return p;
    };

    float* gbuf = (float*)alloc((size_t)B * 128 * 4);
    float* qbuf = (float*)alloc((size_t)B * 4 * 4);

    auto wplane = [&](int elems, __bf16*& hi, __bf16*& lo) {
        hi = (__bf16*)alloc((size_t)elems * 2 * 2);
        lo = hi + elems;
    };
    __bf16 *wa1h, *wa1l, *wa2h, *wa2l, *wd1h, *wd1l, *wd2h, *wd2l, *wr1h, *wr1l, *wr2h, *wr2l;
    wplane(7 * 32 * 64,   wa1h, wa1l);
    wplane(7 * 64 * 32,   wa2h, wa2l);
    wplane(3 * 128 * 64,  wd1h, wd1l);
    wplane(3 * 128 * 128, wd2h, wd2l);
    wplane(3 * 128 * 128, wr1h, wr1l);
    wplane(3 * 128 * 128, wr2h, wr2l);

    const size_t fixed = (off + 255) & ~(size_t)255;
    // activation planes per sample (bytes): hi+lo bf16 channels-last
    const size_t PS = (size_t)2 * 2 * L_LEN * (64 + 32 + 64 + 128 + 128);
    size_t avail = (ws_size > fixed) ? ws_size - fixed - 4096 : 0;
    int chunk = B;
    while (chunk > 1 && (size_t)chunk * PS > avail) chunk >>= 1;

    auto aplane = [&](int C, int c, __bf16*& hi, __bf16*& lo) {
        size_t elems = (size_t)c * L_LEN * C;
        hi = (__bf16*)alloc(elems * 2 * 2);
        lo = hi + elems;
    };
    __bf16 *h0h, *h0l, *a1h, *a1l, *h1h, *h1l, *d1h, *d1l, *d2h, *d2l;
    aplane(64,  chunk, h0h, h0l);
    aplane(32,  chunk, a1h, a1l);
    aplane(64,  chunk, h1h, h1l);
    aplane(128, chunk, d1h, d1l);   // also reused for r1
    aplane(128, chunk, d2h, d2l);
    __bf16 *r1h = d1h, *r1l = d1l;

    // ---- weight prep (tiny) ----
    prep_w_k<64, 32, 7>  <<<dim3((7 * 32 * 64   + 255) / 256), dim3(256), 0, stream>>>(Wa1, wa1h, wa1l);
    prep_w_k<32, 64, 7>  <<<dim3((7 * 64 * 32   + 255) / 256), dim3(256), 0, stream>>>(Wa2, wa2h, wa2l);
    prep_w_k<64, 128, 3> <<<dim3((3 * 128 * 64  + 255) / 256), dim3(256), 0, stream>>>(Wd1, wd1h, wd1l);
    prep_w_k<128, 128, 3><<<dim3((3 * 128 * 128 + 255) / 256), dim3(256), 0, stream>>>(Wd2, wd2h, wd2l);
    prep_w_k<128, 128, 3><<<dim3((3 * 128 * 128 + 255) / 256), dim3(256), 0, stream>>>(Wr1, wr1h, wr1l);
    prep_w_k<128, 128, 3><<<dim3((3 * 128 * 128 + 255) / 256), dim3(256), 0, stream>>>(Wr2, wr2h, wr2l);

    hipMemsetAsync(gbuf, 0, (size_t)B * 128 * sizeof(float), stream);

    const dim3 blk(256);
    for (int s = 0; s < B; s += chunk) {
        const int c = (chunk < B - s) ? chunk : (B - s);
        const dim3 cg(32, 1, c);
        conv1_split_k<<<dim3(64, c), blk, 0, stream>>>(x + (size_t)s * L_LEN, W1, b1, bn1, h0h, h0l);
        conv_mfma_k<64, 32, 7, 1, 0><<<cg, blk, 0, stream>>>(h0h, h0l, wa1h, wa1l, ba1, bna1, nullptr, nullptr, a1h, a1l, nullptr);
        conv_mfma_k<32, 64, 7, 1, 1><<<cg, blk, 0, stream>>>(a1h, a1l, wa2h, wa2l, ba2, bna2, h0h, h0l, h1h, h1l, nullptr);
        conv_mfma_k<64, 128, 3, 2, 0><<<cg, blk, 0, stream>>>(h1h, h1l, wd1h, wd1l, bdd1, bnd1, nullptr, nullptr, d1h, d1l, nullptr);
        conv_mfma_k<128, 128, 3, 4, 0><<<cg, blk, 0, stream>>>(d1h, d1l, wd2h, wd2l, bdd2, bnd2, nullptr, nullptr, d2h, d2l, nullptr);
        conv_mfma_k<128, 128, 3, 1, 0><<<cg, blk, 0, stream>>>(d2h, d2l, wr1h, wr1l, br1, bnr1, nullptr, nullptr, r1h, r1l, nullptr);
        conv_mfma_k<128, 128, 3, 1, 3><<<cg, blk, 0, stream>>>(r1h, r1l, wr2h, wr2l, br2, bnr2, d2h, d2l, nullptr, nullptr, gbuf + (size_t)s * 128);
    }

    quantum_k<<<dim3((B + 127) / 128), dim3(128), 0, stream>>>(gbuf, Wfm, bfm, qw, qbuf, B);
    head_k<<<dim3(B), dim3(64), 0, stream>>>(qbuf, Wf1, bf1, bnf1, Wf2, bf2, bnf2, Wf3, bf3, (float*)d_out);
}

// Round 3
// 1190.639 us; speedup vs baseline: 9.9497x; 1.1823x over previous
//
#include <hip/hip_runtime.h>
#include <math.h>

#define L_LEN 4096
#define DEV __device__ __forceinline__

typedef __attribute__((ext_vector_type(8))) __bf16 bf16x8;
typedef __attribute__((ext_vector_type(4))) float  f32x4;

DEV float silu_f(float x) { return x / (1.f + expf(-x)); }
DEV float sigm_f(float x) { return 1.f / (1.f + expf(-x)); }

DEV void gload16(const void* g, void* l) {
    __builtin_amdgcn_global_load_lds(
        (const __attribute__((address_space(1))) void*)g,
        (__attribute__((address_space(3))) void*)l, 16, 0, 0);
}

// ============================================================================
// conv1: CIN=1, K=5, pad=2 (fp32 direct; writes split hi/lo bf16 channels-last)
// ============================================================================
__global__ __launch_bounds__(256) void conv1_split_k(
    const float* __restrict__ x, const float* __restrict__ W,
    const float* __restrict__ bias, const float* __restrict__ bnp,
    __bf16* __restrict__ outhi, __bf16* __restrict__ outlo)
{
    __shared__ float sw[64 * 5];
    __shared__ float ssc[64], ssh[64];
    const int tid = threadIdx.x;
    if (tid < 64) {
        float g = bnp[tid], be = bnp[64 + tid], mn = bnp[128 + tid], vr = bnp[192 + tid];
        float sc = g * rsqrtf(vr + 1e-5f);
        ssc[tid] = sc;
        ssh[tid] = fmaf(bias[tid] - mn, sc, be);
    }
    for (int i = tid; i < 320; i += 256) sw[i] = W[i];
    __syncthreads();

    const int b = blockIdx.y;
    const int l = blockIdx.x * 64 + (tid >> 2);
    const int cq = (tid & 3) * 16;

    float win[5];
#pragma unroll
    for (int k = 0; k < 5; ++k) {
        int ix = l + k - 2;
        win[k] = (ix >= 0 && ix < L_LEN) ? x[(size_t)b * L_LEN + ix] : 0.f;
    }
    __align__(16) __bf16 vh[16];
    __align__(16) __bf16 vl[16];
#pragma unroll
    for (int j = 0; j < 16; ++j) {
        const int co = cq + j;
        float z = 0.f;
#pragma unroll
        for (int k = 0; k < 5; ++k) z = fmaf(sw[co * 5 + k], win[k], z);
        z = fmaf(z, ssc[co], ssh[co]);
        float v = silu_f(z);
        __bf16 h = (__bf16)v;
        vh[j] = h;
        vl[j] = (__bf16)(v - (float)h);
    }
    const size_t o = ((size_t)b * L_LEN + l) * 64 + cq;
    *(int4*)(outhi + o)     = *(const int4*)(vh);
    *(int4*)(outhi + o + 8) = *(const int4*)(vh + 8);
    *(int4*)(outlo + o)     = *(const int4*)(vl);
    *(int4*)(outlo + o + 8) = *(const int4*)(vl + 8);
}

// ============================================================================
// weight prep -> fragment-order: tile order [s][t][n][pl][lane][8]
//   co = n*16 + (lane&15), ci = s*32 + (lane>>4)*8 + j; pl0=hi, pl1=lo
// ============================================================================
template <int CIN, int COUT, int K>
__global__ void prep_w_k(const float* __restrict__ W, __bf16* __restrict__ wf)
{
    constexpr int NTILE = COUT / 16;
    const int i = blockIdx.x * 256 + threadIdx.x;
    const int total = (CIN / 32) * K * NTILE * 2 * 64;
    if (i >= total) return;
    const int lane = i & 63;
    int r = i >> 6;
    const int pl = r & 1;  r >>= 1;
    const int n  = r % NTILE; r /= NTILE;
    const int t  = r % K;
    const int s  = r / K;

    const int co  = n * 16 + (lane & 15);
    const int cib = s * 32 + (lane >> 4) * 8;
    __align__(16) __bf16 v8[8];
#pragma unroll
    for (int j = 0; j < 8; ++j) {
        const float v = W[((size_t)co * CIN + cib + j) * K + t];
        const __bf16 h = (__bf16)v;
        v8[j] = pl ? (__bf16)(v - (float)h) : h;
    }
    *(int4*)(wf + (size_t)i * 8) = *(const int4*)v8;
}

// ============================================================================
// MFMA split-bf16 implicit-GEMM conv, pipelined (slice,tap) phases.
// Block: 512 thr = 8 waves (4 wl x 2 wc); tile = 256 l x COUT.
// Wave: 4 m-tiles (16l) x NT n-tiles (NT=COUT/32).
// LDS per buffer: [ sW tap-tile (COUT/16)*2 KB | sIn slice (2pl x LWIN x 40) ]
// Phase p=(s,t): stage sW(p+1)->buf[(p+1)&1], sIn(s+1) at t==0 -> buf[(s+1)&1];
// compute from sW buf[p&1], sIn buf[s&1]; vmcnt(0); barrier.
// MODE 0: silu -> split store; MODE 1: aux*sigmoid(z); MODE 3: pool(silu(z+aux))
// ============================================================================
template <int CIN, int COUT, int K, int DIL, int MODE>
__launch_bounds__(512, 2) __global__ void conv_mfma_k(
    const __bf16* __restrict__ inhi, const __bf16* __restrict__ inlo,
    const __bf16* __restrict__ wf,
    const float* __restrict__ bias,  const float* __restrict__ bnp,
    const __bf16* __restrict__ auxhi, const __bf16* __restrict__ auxlo,
    __bf16* __restrict__ outhi, __bf16* __restrict__ outlo,
    float* __restrict__ gsum, const float* __restrict__ zpage)
{
    constexpr int SL    = CIN / 32;
    constexpr int P     = SL * K;
    constexpr int PADR  = ((K - 1) / 2) * DIL;
    constexpr int LWIN  = 256 + (K - 1) * DIL;
    constexpr int NT    = COUT / 32;
    constexpr int SWCH  = (COUT / 16) * 2 * 64;          // 16B chunks per tap-tile
    constexpr int SWB   = SWCH * 16;                     // bytes
    constexpr int CH_IN = 2 * LWIN * 5;                  // 16B chunks per sIn slice
    constexpr int RUP   = (CH_IN + 63) & ~63;
    constexpr int SINB  = RUP * 16;
    constexpr int BUFB  = SWB + SINB;

    __shared__ __align__(16) char smem[2 * BUFB];

    const int tid   = threadIdx.x;
    const int lane  = tid & 63;
    const int w     = tid >> 6;
    const int wl    = w >> 1;                // 0..3
    const int wc    = w & 1;                 // 0..1
    const int b     = blockIdx.z;
    const int l0    = blockIdx.x * 256;
    const int lan15 = lane & 15;
    const int kgB   = (lane >> 4) * 16;      // byte offset of k-group within row

    const size_t bL = (size_t)b * L_LEN;

    // ---------------- staging helpers ----------------
    auto stage_w = [&](int p, int buf) {
        const __bf16* src = wf + (size_t)p * (SWB / 2);
        char* dst = smem + buf * BUFB;
#pragma unroll
        for (int c = tid; c < SWCH; c += 512)
            gload16(src + (size_t)c * 8, dst + (size_t)c * 16);
    };
    auto stage_in = [&](int s, int buf) {
        const int ci0 = s * 32;
        char* dst = smem + buf * BUFB + SWB;
#pragma unroll 2
        for (int c = tid; c < RUP; c += 512) {
            const int pl   = (c >= LWIN * 5) ? 1 : 0;
            const int jj   = c - pl * (LWIN * 5);
            const int r    = jj / 5;
            const int slot = jj - r * 5;
            const int gl   = l0 - PADR + r;
            const bool ok  = (c < CH_IN) & (slot < 4) & (gl >= 0) & (gl < L_LEN);
            const __bf16* s0 = (pl ? inlo : inhi) + ((bL + gl) * CIN + ci0 + slot * 8);
            const void* src = ok ? (const void*)s0 : (const void*)zpage;
            gload16(src, dst + (size_t)c * 16);
        }
    };

    f32x4 acc[4][NT];
#pragma unroll
    for (int mt = 0; mt < 4; ++mt)
#pragma unroll
        for (int nt = 0; nt < NT; ++nt) acc[mt][nt] = (f32x4){0.f, 0.f, 0.f, 0.f};

    // ---------------- prologue ----------------
    stage_in(0, 0);
    stage_w(0, 0);
    asm volatile("s_waitcnt vmcnt(0)" ::: "memory");
    __builtin_amdgcn_s_barrier();
    asm volatile("" ::: "memory");

    int s = 0, t = 0;
#pragma unroll 1
    for (int p = 0; p < P; ++p) {
        // ---- prefetch next phase ----
        if (t == 0 && s + 1 < SL) stage_in(s + 1, (s + 1) & 1);
        if (p + 1 < P) stage_w(p + 1, (p + 1) & 1);

        // ---- compute phase (slice s, tap t) ----
        {
            const char* wbase = smem + (p & 1) * BUFB;
            const char* ibase = smem + (s & 1) * BUFB + SWB;
            bf16x8 bh[NT], bl[NT];
#pragma unroll
            for (int nt = 0; nt < NT; ++nt) {
                const int ntg = wc * NT + nt;
                bh[nt] = *(const bf16x8*)(wbase + (ntg * 2 + 0) * 1024 + lane * 16);
                bl[nt] = *(const bf16x8*)(wbase + (ntg * 2 + 1) * 1024 + lane * 16);
            }
#pragma unroll
            for (int mt = 0; mt < 4; ++mt) {
                const int row = wl * 64 + mt * 16 + lan15 + t * DIL;
                const bf16x8 ah = *(const bf16x8*)(ibase + row * 80 + kgB);
                const bf16x8 al = *(const bf16x8*)(ibase + (LWIN + row) * 80 + kgB);
#pragma unroll
                for (int nt = 0; nt < NT; ++nt) {
                    acc[mt][nt] = __builtin_amdgcn_mfma_f32_16x16x32_bf16(ah, bh[nt], acc[mt][nt], 0, 0, 0);
                    acc[mt][nt] = __builtin_amdgcn_mfma_f32_16x16x32_bf16(ah, bl[nt], acc[mt][nt], 0, 0, 0);
                    acc[mt][nt] = __builtin_amdgcn_mfma_f32_16x16x32_bf16(al, bh[nt], acc[mt][nt], 0, 0, 0);
                }
            }
        }

        asm volatile("s_waitcnt vmcnt(0)" ::: "memory");
        __builtin_amdgcn_s_barrier();
        asm volatile("" ::: "memory");

        if (++t == K) { t = 0; ++s; }
    }

    // ---------------- epilogue ----------------
#pragma unroll
    for (int nt = 0; nt < NT; ++nt) {
        const int co = (wc * NT + nt) * 16 + lan15;
        const float g = bnp[co], be = bnp[COUT + co], mn = bnp[2 * COUT + co], vr = bnp[3 * COUT + co];
        const float sc = g * rsqrtf(vr + 1e-5f);
        const float sh = fmaf(bias[co] - mn, sc, be);
        float ps = 0.f;
#pragma unroll
        for (int mt = 0; mt < 4; ++mt) {
#pragma unroll
            for (int r = 0; r < 4; ++r) {
                const int l = l0 + wl * 64 + mt * 16 + (lane >> 4) * 4 + r;
                const size_t gidx = (bL + l) * COUT + co;
                const float z = fmaf(acc[mt][nt][r], sc, sh);
                if constexpr (MODE == 0) {
                    const float v = silu_f(z);
                    const __bf16 hb = (__bf16)v;
                    outhi[gidx] = hb;
                    outlo[gidx] = (__bf16)(v - (float)hb);
                } else if constexpr (MODE == 1) {
                    const float gate = (float)auxhi[gidx] + (float)auxlo[gidx];
                    const float v = gate * sigm_f(z);
                    const __bf16 hb = (__bf16)v;
                    outhi[gidx] = hb;
                    outlo[gidx] = (__bf16)(v - (float)hb);
                } else {
                    const float res = (float)auxhi[gidx] + (float)auxlo[gidx];
                    ps += silu_f(z + res);
                }
            }
        }
        if constexpr (MODE == 3) {
            ps += __shfl_down(ps, 32, 64);
            ps += __shfl_down(ps, 16, 64);
            if ((lane >> 4) == 0) atomicAdd(&gsum[b * COUT + co], ps);
        }
    }
}

// ============================================================================
// 4-qubit statevector circuit, one thread per batch row
// ============================================================================
template <int BW> DEV void g_ry(float (&re)[16], float (&im)[16], float t) {
    float s, c; sincosf(0.5f * t, &s, &c);
#pragma unroll
    for (int i = 0; i < 16; ++i)
        if (!(i & BW)) {
            const int j = i | BW;
            float r0 = re[i], q0 = im[i], r1 = re[j], q1 = im[j];
            re[i] = c * r0 - s * r1; im[i] = c * q0 - s * q1;
            re[j] = s * r0 + c * r1; im[j] = s * q0 + c * q1;
        }
}
template <int BW> DEV void g_rz(float (&re)[16], float (&im)[16], float t) {
    float s, c; sincosf(0.5f * t, &s, &c);
#pragma unroll
    for (int i = 0; i < 16; ++i) {
        float r = re[i], q = im[i];
        if (i & BW) { re[i] = r * c - q * s; im[i] = q * c + r * s; }
        else        { re[i] = r * c + q * s; im[i] = q * c - r * s; }
    }
}
template <int BC, int BT> DEV void g_cnot(float (&re)[16], float (&im)[16]) {
#pragma unroll
    for (int i = 0; i < 16; ++i)
        if ((i & BC) && !(i & BT)) {
            const int j = i | BT;
            float r = re[i]; re[i] = re[j]; re[j] = r;
            float q = im[i]; im[i] = im[j]; im[j] = q;
        }
}

__global__ void quantum_k(const float* __restrict__ gsum, const float* __restrict__ Wfm,
                          const float* __restrict__ bfm, const float* __restrict__ qw,
                          float* __restrict__ q, int B)
{
    const int b = blockIdx.x * blockDim.x + threadIdx.x;
    if (b >= B) return;

    float qin[4];
#pragma unroll
    for (int j = 0; j < 4; ++j) qin[j] = bfm[j];
    const float inv = 1.f / (float)L_LEN;
    for (int c = 0; c < 128; ++c) {
        const float gv = gsum[b * 128 + c] * inv;
#pragma unroll
        for (int j = 0; j < 4; ++j) qin[j] = fmaf(gv, Wfm[j * 128 + c], qin[j]);
    }

    float re[16], im[16];
#pragma unroll
    for (int i = 0; i < 16; ++i) { re[i] = 0.f; im[i] = 0.f; }
    re[0] = 1.f;

    g_ry<8>(re, im, qin[0]); g_ry<4>(re, im, qin[1]); g_ry<2>(re, im, qin[2]); g_ry<1>(re, im, qin[3]);
    g_rz<8>(re, im, qw[0]);  g_ry<8>(re, im, qw[1]);
    g_rz<4>(re, im, qw[2]);  g_ry<4>(re, im, qw[3]);
    g_rz<2>(re, im, qw[4]);  g_ry<2>(re, im, qw[5]);
    g_rz<1>(re, im, qw[6]);  g_ry<1>(re, im, qw[7]);
    g_cnot<8, 4>(re, im); g_cnot<4, 2>(re, im); g_cnot<2, 1>(re, im);
    g_rz<8>(re, im, qw[8]);  g_ry<8>(re, im, qw[9]);
    g_rz<4>(re, im, qw[10]); g_ry<4>(re, im, qw[11]);
    g_rz<2>(re, im, qw[12]); g_ry<2>(re, im, qw[13]);
    g_rz<1>(re, im, qw[14]); g_ry<1>(re, im, qw[15]);

    float p[16];
#pragma unroll
    for (int i = 0; i < 16; ++i) p[i] = re[i] * re[i] + im[i] * im[i];
#pragma unroll
    for (int w = 0; w < 4; ++w) {
        const int bw = 8 >> w;
        float e = 0.f;
#pragma unroll
        for (int i = 0; i < 16; ++i) e += (i & bw) ? -p[i] : p[i];
        q[b * 4 + w] = e;
    }
}

// ============================================================================
// FC head: 4 -> 64 -> 32 -> 1
// ============================================================================
__global__ void head_k(const float* __restrict__ q,
                       const float* __restrict__ Wf1, const float* __restrict__ bf1, const float* __restrict__ bnf1,
                       const float* __restrict__ Wf2, const float* __restrict__ bf2, const float* __restrict__ bnf2,
                       const float* __restrict__ Wf3, const float* __restrict__ bf3,
                       float* __restrict__ out)
{
    const int b = blockIdx.x, t = threadIdx.x;
    __shared__ float qs[4], x1[64], x2[32];
    if (t < 4) qs[t] = q[b * 4 + t];
    __syncthreads();
    {
        float a = bf1[t];
#pragma unroll
        for (int k = 0; k < 4; ++k) a = fmaf(qs[k], Wf1[t * 4 + k], a);
        const float sc = bnf1[t] / sqrtf(bnf1[192 + t] + 1e-5f);
        const float z  = (a - bnf1[128 + t]) * sc + bnf1[64 + t];
        x1[t] = silu_f(z);
    }
    __syncthreads();
    if (t < 32) {
        float a = bf2[t];
        for (int k = 0; k < 64; ++k) a = fmaf(x1[k], Wf2[t * 64 + k], a);
        const float sc = bnf2[t] / sqrtf(bnf2[96 + t] + 1e-5f);
        const float z  = (a - bnf2[64 + t]) * sc + bnf2[32 + t];
        x2[t] = silu_f(z);
    }
    __syncthreads();
    if (t == 0) {
        float a = bf3[0];
        for (int k = 0; k < 32; ++k) a = fmaf(x2[k], Wf3[k], a);
        out[b] = a;
    }
}

// ============================================================================
extern "C" void kernel_launch(void* const* d_in, const int* in_sizes, int n_in,
                              void* d_out, int out_size, void* d_ws, size_t ws_size,
                              hipStream_t stream)
{
    (void)n_in; (void)out_size;
    const float* x    = (const float*)d_in[0];
    const float* W1   = (const float*)d_in[1];
    const float* b1   = (const float*)d_in[2];
    const float* bn1  = (const float*)d_in[3];
    const float* Wa1  = (const float*)d_in[4];
    const float* ba1  = (const float*)d_in[5];
    const float* bna1 = (const float*)d_in[6];
    const float* Wa2  = (const float*)d_in[7];
    const float* ba2  = (const float*)d_in[8];
    const float* bna2 = (const float*)d_in[9];
    const float* Wd1  = (const float*)d_in[10];
    const float* bdd1 = (const float*)d_in[11];
    const float* bnd1 = (const float*)d_in[12];
    const float* Wd2  = (const float*)d_in[13];
    const float* bdd2 = (const float*)d_in[14];
    const float* bnd2 = (const float*)d_in[15];
    const float* Wr1  = (const float*)d_in[16];
    const float* br1  = (const float*)d_in[17];
    const float* bnr1 = (const float*)d_in[18];
    const float* Wr2  = (const float*)d_in[19];
    const float* br2  = (const float*)d_in[20];
    const float* bnr2 = (const float*)d_in[21];
    const float* Wfm  = (const float*)d_in[22];
    const float* bfm  = (const float*)d_in[23];
    const float* qw   = (const float*)d_in[24];
    const float* Wf1  = (const float*)d_in[25];
    const float* bf1  = (const float*)d_in[26];
    const float* bnf1 = (const float*)d_in[27];
    const float* Wf2  = (const float*)d_in[28];
    const float* bf2  = (const float*)d_in[29];
    const float* bnf2 = (const float*)d_in[30];
    const float* Wf3  = (const float*)d_in[31];
    const float* bf3  = (const float*)d_in[32];

    const int B = in_sizes[0] / L_LEN;  // 128

    // ---- workspace carve (256B aligned bump allocator) ----
    char* base = (char*)d_ws;
    size_t off = 0;
    auto alloc = [&](size_t bytes) -> char* {
        off = (off + 255) & ~(size_t)255;
        char* p = base + off;
        off += bytes;
        return p;
    };

    float* gbuf  = (float*)alloc((size_t)B * 128 * 4);
    float* qbuf  = (float*)alloc((size_t)B * 4 * 4);
    float* zpage = (float*)alloc(256);

    // fragment-order weight buffers: elems = SL*K*(COUT/16)*2*64*8 = K*COUT*CIN*2
    auto wfrag = [&](int cin, int cout, int k) -> __bf16* {
        return (__bf16*)alloc((size_t)k * cout * cin * 2 * 2);
    };
    __bf16* wa1f = wfrag(64, 32, 7);
    __bf16* wa2f = wfrag(32, 64, 7);
    __bf16* wd1f = wfrag(64, 128, 3);
    __bf16* wd2f = wfrag(128, 128, 3);
    __bf16* wr1f = wfrag(128, 128, 3);
    __bf16* wr2f = wfrag(128, 128, 3);

    const size_t fixed = (off + 255) & ~(size_t)255;
    const size_t PS = (size_t)2 * 2 * L_LEN * (64 + 32 + 64 + 128 + 128);
    size_t avail = (ws_size > fixed + 4096) ? ws_size - fixed - 4096 : 0;
    int chunk = B;
    while (chunk > 1 && (size_t)chunk * PS > avail) chunk >>= 1;

    auto aplane = [&](int C, int c, __bf16*& hi, __bf16*& lo) {
        size_t elems = (size_t)c * L_LEN * C;
        hi = (__bf16*)alloc(elems * 2 * 2);
        lo = hi + elems;
    };
    __bf16 *h0h, *h0l, *a1h, *a1l, *h1h, *h1l, *d1h, *d1l, *d2h, *d2l;
    aplane(64,  chunk, h0h, h0l);
    aplane(32,  chunk, a1h, a1l);
    aplane(64,  chunk, h1h, h1l);
    aplane(128, chunk, d1h, d1l);   // also reused for r1
    aplane(128, chunk, d2h, d2l);
    __bf16 *r1h = d1h, *r1l = d1l;

    // ---- weight prep (tiny) ----
    auto pg = [](int tot) { return dim3((tot + 255) / 256); };
    prep_w_k<64, 32, 7>  <<<pg(2*7*2*2*64),  dim3(256), 0, stream>>>(Wa1, wa1f);
    prep_w_k<32, 64, 7>  <<<pg(1*7*4*2*64),  dim3(256), 0, stream>>>(Wa2, wa2f);
    prep_w_k<64, 128, 3> <<<pg(2*3*8*2*64),  dim3(256), 0, stream>>>(Wd1, wd1f);
    prep_w_k<128, 128, 3><<<pg(4*3*8*2*64),  dim3(256), 0, stream>>>(Wd2, wd2f);
    prep_w_k<128, 128, 3><<<pg(4*3*8*2*64),  dim3(256), 0, stream>>>(Wr1, wr1f);
    prep_w_k<128, 128, 3><<<pg(4*3*8*2*64),  dim3(256), 0, stream>>>(Wr2, wr2f);

    hipMemsetAsync(gbuf, 0, (size_t)B * 128 * sizeof(float), stream);
    hipMemsetAsync(zpage, 0, 256, stream);

    const dim3 blk(512);
    for (int sft = 0; sft < B; sft += chunk) {
        const int c = (chunk < B - sft) ? chunk : (B - sft);
        const dim3 cg(L_LEN / 256, 1, c);
        conv1_split_k<<<dim3(64, c), dim3(256), 0, stream>>>(x + (size_t)sft * L_LEN, W1, b1, bn1, h0h, h0l);
        conv_mfma_k<64, 32, 7, 1, 0><<<cg, blk, 0, stream>>>(h0h, h0l, wa1f, ba1, bna1, nullptr, nullptr, a1h, a1l, nullptr, zpage);
        conv_mfma_k<32, 64, 7, 1, 1><<<cg, blk, 0, stream>>>(a1h, a1l, wa2f, ba2, bna2, h0h, h0l, h1h, h1l, nullptr, zpage);
        conv_mfma_k<64, 128, 3, 2, 0><<<cg, blk, 0, stream>>>(h1h, h1l, wd1f, bdd1, bnd1, nullptr, nullptr, d1h, d1l, nullptr, zpage);
        conv_mfma_k<128, 128, 3, 4, 0><<<cg, blk, 0, stream>>>(d1h, d1l, wd2f, bdd2, bnd2, nullptr, nullptr, d2h, d2l, nullptr, zpage);
        conv_mfma_k<128, 128, 3, 1, 0><<<cg, blk, 0, stream>>>(d2h, d2l, wr1f, br1, bnr1, nullptr, nullptr, r1h, r1l, nullptr, zpage);
        conv_mfma_k<128, 128, 3, 1, 3><<<cg, blk, 0, stream>>>(r1h, r1l, wr2f, br2, bnr2, d2h, d2l, nullptr, nullptr, gbuf + (size_t)sft * 128, zpage);
    }

    quantum_k<<<dim3((B + 127) / 128), dim3(128), 0, stream>>>(gbuf, Wfm, bfm, qw, qbuf, B);
    head_k<<<dim3(B), dim3(64), 0, stream>>>(qbuf, Wf1, bf1, bnf1, Wf2, bf2, bnf2, Wf3, bf3, (float*)d_out);
}

// Round 5
// 1129.951 us; speedup vs baseline: 10.4841x; 1.0537x over previous
//
#include <hip/hip_runtime.h>
#include <math.h>

#define L_LEN 4096
#define DEV __device__ __forceinline__

typedef __attribute__((ext_vector_type(8))) __bf16 bf16x8;
typedef __attribute__((ext_vector_type(4))) float  f32x4;

DEV float silu_f(float x) { return x / (1.f + expf(-x)); }
DEV float sigm_f(float x) { return 1.f / (1.f + expf(-x)); }

DEV void gload16(const void* g, void* l) {
    __builtin_amdgcn_global_load_lds(
        (const __attribute__((address_space(1))) void*)g,
        (__attribute__((address_space(3))) void*)l, 16, 0, 0);
}

// ============================================================================
// conv1: CIN=1, K=5, pad=2 (fp32 direct; writes split hi/lo bf16 channels-last)
// ============================================================================
__global__ __launch_bounds__(256) void conv1_split_k(
    const float* __restrict__ x, const float* __restrict__ W,
    const float* __restrict__ bias, const float* __restrict__ bnp,
    __bf16* __restrict__ outhi, __bf16* __restrict__ outlo)
{
    __shared__ float sw[64 * 5];
    __shared__ float ssc[64], ssh[64];
    const int tid = threadIdx.x;
    if (tid < 64) {
        float g = bnp[tid], be = bnp[64 + tid], mn = bnp[128 + tid], vr = bnp[192 + tid];
        float sc = g * rsqrtf(vr + 1e-5f);
        ssc[tid] = sc;
        ssh[tid] = fmaf(bias[tid] - mn, sc, be);
    }
    for (int i = tid; i < 320; i += 256) sw[i] = W[i];
    __syncthreads();

    const int b = blockIdx.y;
    const int l = blockIdx.x * 64 + (tid >> 2);
    const int cq = (tid & 3) * 16;

    float win[5];
#pragma unroll
    for (int k = 0; k < 5; ++k) {
        int ix = l + k - 2;
        win[k] = (ix >= 0 && ix < L_LEN) ? x[(size_t)b * L_LEN + ix] : 0.f;
    }
    __align__(16) __bf16 vh[16];
    __align__(16) __bf16 vl[16];
#pragma unroll
    for (int j = 0; j < 16; ++j) {
        const int co = cq + j;
        float z = 0.f;
#pragma unroll
        for (int k = 0; k < 5; ++k) z = fmaf(sw[co * 5 + k], win[k], z);
        z = fmaf(z, ssc[co], ssh[co]);
        float v = silu_f(z);
        __bf16 h = (__bf16)v;
        vh[j] = h;
        vl[j] = (__bf16)(v - (float)h);
    }
    const size_t o = ((size_t)b * L_LEN + l) * 64 + cq;
    *(int4*)(outhi + o)     = *(const int4*)(vh);
    *(int4*)(outhi + o + 8) = *(const int4*)(vh + 8);
    *(int4*)(outlo + o)     = *(const int4*)(vl);
    *(int4*)(outlo + o + 8) = *(const int4*)(vl + 8);
}

// ============================================================================
// weight prep -> fragment-order: [s][t][n][pl][lane][8]
//   co = n*16 + (lane&15), ci = s*32 + (lane>>4)*8 + j; pl0=hi, pl1=lo
// ============================================================================
template <int CIN, int COUT, int K>
__global__ void prep_w_k(const float* __restrict__ W, __bf16* __restrict__ wf)
{
    constexpr int NTILE = COUT / 16;
    const int i = blockIdx.x * 256 + threadIdx.x;
    const int total = (CIN / 32) * K * NTILE * 2 * 64;
    if (i >= total) return;
    const int lane = i & 63;
    int r = i >> 6;
    const int pl = r & 1;  r >>= 1;
    const int n  = r % NTILE; r /= NTILE;
    const int t  = r % K;
    const int s  = r / K;

    const int co  = n * 16 + (lane & 15);
    const int cib = s * 32 + (lane >> 4) * 8;
    __align__(16) __bf16 v8[8];
#pragma unroll
    for (int j = 0; j < 8; ++j) {
        const float v = W[((size_t)co * CIN + cib + j) * K + t];
        const __bf16 h = (__bf16)v;
        v8[j] = pl ? (__bf16)(v - (float)h) : h;
    }
    *(int4*)(wf + (size_t)i * 8) = *(const int4*)v8;
}

// ============================================================================
// MFMA split-bf16 implicit-GEMM conv — fully static phase unroll.
// Block: 256 thr = 4 waves (2 wl x 2 wc); tile = 128 l x COUT.
// Wave: 4 m-tiles (64 l) x NT n-tiles (NT = COUT/32); acc[4][NT].
// A (input window) in LDS, DOUBLE-buffered per ci-slice: slice s+1 staged
// into buf[(s+1)&1] at slice-s start; one vmcnt(0)+sched_barrier+__syncthreads
// per slice boundary. B (weights, fragment-order) loaded per phase straight
// from global/L2 into fresh registers (compiler pipelines across unroll).
// MODE 0: silu; MODE 1: aux*sigmoid(z) (in-place safe); MODE 3: pooled silu
// ============================================================================
template <int CIN, int COUT, int K, int DIL, int MODE>
__launch_bounds__(256, 2) __global__ void conv_mfma_k(
    const __bf16* __restrict__ inhi, const __bf16* __restrict__ inlo,
    const __bf16* __restrict__ wf,
    const float* __restrict__ bias,  const float* __restrict__ bnp,
    const __bf16* __restrict__ auxhi, const __bf16* __restrict__ auxlo,
    __bf16* __restrict__ outhi, __bf16* __restrict__ outlo,
    float* __restrict__ gsum, const float* __restrict__ zpage)
{
    constexpr int SL    = CIN / 32;
    constexpr int P     = SL * K;
    constexpr int PADR  = ((K - 1) / 2) * DIL;
    constexpr int LWIN  = 128 + (K - 1) * DIL;
    constexpr int NT    = COUT / 32;
    constexpr int NTILE = COUT / 16;
    constexpr int CH_IN = 2 * LWIN * 5;       // 16B chunks per slice (slot4 = pad)
    constexpr int BUFB  = LWIN * 80 * 2;      // bytes per buffer (hi+lo planes)

    __shared__ __align__(16) char smem[2 * BUFB];

    const int tid   = threadIdx.x;
    const int lane  = tid & 63;
    const int w     = tid >> 6;
    const int wl    = w >> 1;                 // 0..1 : l half (64 rows)
    const int wc    = w & 1;                  // 0..1 : co half
    const int b     = blockIdx.z;
    const int l0    = blockIdx.x * 128;
    const int lan15 = lane & 15;
    const int kgB   = (lane >> 4) * 16;

    const size_t bL = (size_t)b * L_LEN;

    // ---- stage input-window slice s into LDS buffer buf (lane-linear dst) ----
    auto stage_in = [&](int s, int buf) {
        const int ci0 = s * 32;
        char* dst = smem + buf * BUFB;
        for (int c = tid; c < CH_IN; c += 256) {
            const int pl   = (c >= LWIN * 5) ? 1 : 0;
            const int j    = c - pl * (LWIN * 5);
            const int row  = j / 5;
            const int slot = j - row * 5;
            const int gl   = l0 - PADR + row;
            const bool ok  = (slot < 4) & (gl >= 0) & (gl < L_LEN);
            const __bf16* s0 = (pl ? inlo : inhi) + ((bL + gl) * CIN + ci0 + slot * 8);
            const void* src = ok ? (const void*)s0 : (const void*)zpage;
            gload16(src, dst + (size_t)c * 16);
        }
    };

    f32x4 acc[4][NT];
#pragma unroll
    for (int mt = 0; mt < 4; ++mt)
#pragma unroll
        for (int nt = 0; nt < NT; ++nt) acc[mt][nt] = (f32x4){0.f, 0.f, 0.f, 0.f};

    // ---- prologue: stage slice 0 ----
    stage_in(0, 0);
    asm volatile("s_waitcnt vmcnt(0)" ::: "memory");
    __builtin_amdgcn_sched_barrier(0);
    __syncthreads();

    // ---- fully static phase loop ----
#pragma unroll
    for (int pp = 0; pp < P; ++pp) {
        const int ss = pp / K;
        const int tt = pp % K;

        if (tt == 0 && ss + 1 < SL) stage_in(ss + 1, (ss + 1) & 1);

        // B fragments for this phase, straight from global (L2-hot)
        bf16x8 br[2 * NT];
        {
            const __bf16* bbase = wf + (size_t)pp * (NTILE * 1024);
#pragma unroll
            for (int nt = 0; nt < NT; ++nt) {
                const int ntg = wc * NT + nt;
                br[nt * 2 + 0] = *(const bf16x8*)(bbase + (ntg * 2 + 0) * 512 + lane * 8);
                br[nt * 2 + 1] = *(const bf16x8*)(bbase + (ntg * 2 + 1) * 512 + lane * 8);
            }
        }

        const char* ibase = smem + (ss & 1) * BUFB;
#pragma unroll
        for (int mt = 0; mt < 4; ++mt) {
            const int row = wl * 64 + mt * 16 + lan15 + tt * DIL;
            const bf16x8 ah = *(const bf16x8*)(ibase + row * 80 + kgB);
            const bf16x8 al = *(const bf16x8*)(ibase + LWIN * 80 + row * 80 + kgB);
#pragma unroll
            for (int nt = 0; nt < NT; ++nt) {
                acc[mt][nt] = __builtin_amdgcn_mfma_f32_16x16x32_bf16(ah, br[nt * 2 + 0], acc[mt][nt], 0, 0, 0);
                acc[mt][nt] = __builtin_amdgcn_mfma_f32_16x16x32_bf16(ah, br[nt * 2 + 1], acc[mt][nt], 0, 0, 0);
                acc[mt][nt] = __builtin_amdgcn_mfma_f32_16x16x32_bf16(al, br[nt * 2 + 0], acc[mt][nt], 0, 0, 0);
            }
        }

        // slice boundary: staged slice ss+1 landed; all reads of buf[ss&1] done
        if (tt == K - 1 && ss + 1 < SL) {
            asm volatile("s_waitcnt vmcnt(0)" ::: "memory");
            __builtin_amdgcn_sched_barrier(0);
            __syncthreads();
        }
    }

    // ---------------- epilogue ----------------
#pragma unroll
    for (int nt = 0; nt < NT; ++nt) {
        const int co = (wc * NT + nt) * 16 + lan15;
        const float g = bnp[co], be = bnp[COUT + co], mn = bnp[2 * COUT + co], vr = bnp[3 * COUT + co];
        const float sc = g * rsqrtf(vr + 1e-5f);
        const float sh = fmaf(bias[co] - mn, sc, be);
        float ps = 0.f;
#pragma unroll
        for (int mt = 0; mt < 4; ++mt) {
#pragma unroll
            for (int r = 0; r < 4; ++r) {
                const int l = l0 + wl * 64 + mt * 16 + (lane >> 4) * 4 + r;
                const size_t gidx = (bL + l) * COUT + co;
                const float z = fmaf(acc[mt][nt][r], sc, sh);
                if constexpr (MODE == 0) {
                    const float v = silu_f(z);
                    const __bf16 hb = (__bf16)v;
                    outhi[gidx] = hb;
                    outlo[gidx] = (__bf16)(v - (float)hb);
                } else if constexpr (MODE == 1) {
                    const float gate = (float)auxhi[gidx] + (float)auxlo[gidx];
                    const float v = gate * sigm_f(z);
                    const __bf16 hb = (__bf16)v;
                    outhi[gidx] = hb;
                    outlo[gidx] = (__bf16)(v - (float)hb);
                } else {
                    const float res = (float)auxhi[gidx] + (float)auxlo[gidx];
                    ps += silu_f(z + res);
                }
            }
        }
        if constexpr (MODE == 3) {
            ps += __shfl_down(ps, 32, 64);
            ps += __shfl_down(ps, 16, 64);
            if ((lane >> 4) == 0) atomicAdd(&gsum[b * COUT + co], ps);
        }
    }
}

// ============================================================================
// 4-qubit statevector circuit, one thread per batch row
// ============================================================================
template <int BW> DEV void g_ry(float (&re)[16], float (&im)[16], float t) {
    float s, c; sincosf(0.5f * t, &s, &c);
#pragma unroll
    for (int i = 0; i < 16; ++i)
        if (!(i & BW)) {
            const int j = i | BW;
            float r0 = re[i], q0 = im[i], r1 = re[j], q1 = im[j];
            re[i] = c * r0 - s * r1; im[i] = c * q0 - s * q1;
            re[j] = s * r0 + c * r1; im[j] = s * q0 + c * q1;
        }
}
template <int BW> DEV void g_rz(float (&re)[16], float (&im)[16], float t) {
    float s, c; sincosf(0.5f * t, &s, &c);
#pragma unroll
    for (int i = 0; i < 16; ++i) {
        float r = re[i], q = im[i];
        if (i & BW) { re[i] = r * c - q * s; im[i] = q * c + r * s; }
        else        { re[i] = r * c + q * s; im[i] = q * c - r * s; }
    }
}
template <int BC, int BT> DEV void g_cnot(float (&re)[16], float (&im)[16]) {
#pragma unroll
    for (int i = 0; i < 16; ++i)
        if ((i & BC) && !(i & BT)) {
            const int j = i | BT;
            float r = re[i]; re[i] = re[j]; re[j] = r;
            float q = im[i]; im[i] = im[j]; im[j] = q;
        }
}

__global__ void quantum_k(const float* __restrict__ gsum, const float* __restrict__ Wfm,
                          const float* __restrict__ bfm, const float* __restrict__ qw,
                          float* __restrict__ q, int B)
{
    const int b = blockIdx.x * blockDim.x + threadIdx.x;
    if (b >= B) return;

    float qin[4];
#pragma unroll
    for (int j = 0; j < 4; ++j) qin[j] = bfm[j];
    const float inv = 1.f / (float)L_LEN;
    for (int c = 0; c < 128; ++c) {
        const float gv = gsum[b * 128 + c] * inv;
#pragma unroll
        for (int j = 0; j < 4; ++j) qin[j] = fmaf(gv, Wfm[j * 128 + c], qin[j]);
    }

    float re[16], im[16];
#pragma unroll
    for (int i = 0; i < 16; ++i) { re[i] = 0.f; im[i] = 0.f; }
    re[0] = 1.f;

    g_ry<8>(re, im, qin[0]); g_ry<4>(re, im, qin[1]); g_ry<2>(re, im, qin[2]); g_ry<1>(re, im, qin[3]);
    g_rz<8>(re, im, qw[0]);  g_ry<8>(re, im, qw[1]);
    g_rz<4>(re, im, qw[2]);  g_ry<4>(re, im, qw[3]);
    g_rz<2>(re, im, qw[4]);  g_ry<2>(re, im, qw[5]);
    g_rz<1>(re, im, qw[6]);  g_ry<1>(re, im, qw[7]);
    g_cnot<8, 4>(re, im); g_cnot<4, 2>(re, im); g_cnot<2, 1>(re, im);
    g_rz<8>(re, im, qw[8]);  g_ry<8>(re, im, qw[9]);
    g_rz<4>(re, im, qw[10]); g_ry<4>(re, im, qw[11]);
    g_rz<2>(re, im, qw[12]); g_ry<2>(re, im, qw[13]);
    g_rz<1>(re, im, qw[14]); g_ry<1>(re, im, qw[15]);

    float pr[16];
#pragma unroll
    for (int i = 0; i < 16; ++i) pr[i] = re[i] * re[i] + im[i] * im[i];
#pragma unroll
    for (int w = 0; w < 4; ++w) {
        const int bw = 8 >> w;
        float e = 0.f;
#pragma unroll
        for (int i = 0; i < 16; ++i) e += (i & bw) ? -pr[i] : pr[i];
        q[b * 4 + w] = e;
    }
}

// ============================================================================
// FC head: 4 -> 64 -> 32 -> 1
// ============================================================================
__global__ void head_k(const float* __restrict__ q,
                       const float* __restrict__ Wf1, const float* __restrict__ bf1, const float* __restrict__ bnf1,
                       const float* __restrict__ Wf2, const float* __restrict__ bf2, const float* __restrict__ bnf2,
                       const float* __restrict__ Wf3, const float* __restrict__ bf3,
                       float* __restrict__ out)
{
    const int b = blockIdx.x, t = threadIdx.x;
    __shared__ float qs[4], x1[64], x2[32];
    if (t < 4) qs[t] = q[b * 4 + t];
    __syncthreads();
    {
        float a = bf1[t];
#pragma unroll
        for (int k = 0; k < 4; ++k) a = fmaf(qs[k], Wf1[t * 4 + k], a);
        const float sc = bnf1[t] / sqrtf(bnf1[192 + t] + 1e-5f);
        const float z  = (a - bnf1[128 + t]) * sc + bnf1[64 + t];
        x1[t] = silu_f(z);
    }
    __syncthreads();
    if (t < 32) {
        float a = bf2[t];
        for (int k = 0; k < 64; ++k) a = fmaf(x1[k], Wf2[t * 64 + k], a);
        const float sc = bnf2[t] / sqrtf(bnf2[96 + t] + 1e-5f);
        const float z  = (a - bnf2[64 + t]) * sc + bnf2[32 + t];
        x2[t] = silu_f(z);
    }
    __syncthreads();
    if (t == 0) {
        float a = bf3[0];
        for (int k = 0; k < 32; ++k) a = fmaf(x2[k], Wf3[k], a);
        out[b] = a;
    }
}

// ============================================================================
extern "C" void kernel_launch(void* const* d_in, const int* in_sizes, int n_in,
                              void* d_out, int out_size, void* d_ws, size_t ws_size,
                              hipStream_t stream)
{
    (void)n_in; (void)out_size;
    const float* x    = (const float*)d_in[0];
    const float* W1   = (const float*)d_in[1];
    const float* b1   = (const float*)d_in[2];
    const float* bn1  = (const float*)d_in[3];
    const float* Wa1  = (const float*)d_in[4];
    const float* ba1  = (const float*)d_in[5];
    const float* bna1 = (const float*)d_in[6];
    const float* Wa2  = (const float*)d_in[7];
    const float* ba2  = (const float*)d_in[8];
    const float* bna2 = (const float*)d_in[9];
    const float* Wd1  = (const float*)d_in[10];
    const float* bdd1 = (const float*)d_in[11];
    const float* bnd1 = (const float*)d_in[12];
    const float* Wd2  = (const float*)d_in[13];
    const float* bdd2 = (const float*)d_in[14];
    const float* bnd2 = (const float*)d_in[15];
    const float* Wr1  = (const float*)d_in[16];
    const float* br1  = (const float*)d_in[17];
    const float* bnr1 = (const float*)d_in[18];
    const float* Wr2  = (const float*)d_in[19];
    const float* br2  = (const float*)d_in[20];
    const float* bnr2 = (const float*)d_in[21];
    const float* Wfm  = (const float*)d_in[22];
    const float* bfm  = (const float*)d_in[23];
    const float* qw   = (const float*)d_in[24];
    const float* Wf1  = (const float*)d_in[25];
    const float* bf1  = (const float*)d_in[26];
    const float* bnf1 = (const float*)d_in[27];
    const float* Wf2  = (const float*)d_in[28];
    const float* bf2  = (const float*)d_in[29];
    const float* bnf2 = (const float*)d_in[30];
    const float* Wf3  = (const float*)d_in[31];
    const float* bf3  = (const float*)d_in[32];

    const int B = in_sizes[0] / L_LEN;  // 128

    // ---- workspace carve (256B aligned bump allocator) ----
    char* base = (char*)d_ws;
    size_t off = 0;
    auto alloc = [&](size_t bytes) -> char* {
        off = (off + 255) & ~(size_t)255;
        char* p = base + off;
        off += bytes;
        return p;
    };

    float* gbuf  = (float*)alloc((size_t)B * 128 * 4);
    float* qbuf  = (float*)alloc((size_t)B * 4 * 4);
    float* zpage = (float*)alloc(256);

    auto wfrag = [&](int cin, int cout, int k) -> __bf16* {
        return (__bf16*)alloc((size_t)k * cout * cin * 2 * 2);
    };
    __bf16* wa1f = wfrag(64, 32, 7);
    __bf16* wa2f = wfrag(32, 64, 7);
    __bf16* wd1f = wfrag(64, 128, 3);
    __bf16* wd2f = wfrag(128, 128, 3);
    __bf16* wr1f = wfrag(128, 128, 3);
    __bf16* wr2f = wfrag(128, 128, 3);

    const size_t fixed = (off + 255) & ~(size_t)255;
    const size_t PS = (size_t)2 * 2 * L_LEN * (64 + 32 + 128 + 128);
    size_t avail = (ws_size > fixed + 4096) ? ws_size - fixed - 4096 : 0;
    int chunk = B;
    while (chunk > 1 && (size_t)chunk * PS > avail) chunk >>= 1;

    auto aplane = [&](int C, int c, __bf16*& hi, __bf16*& lo) {
        size_t elems = (size_t)c * L_LEN * C;
        hi = (__bf16*)alloc(elems * 2 * 2);
        lo = hi + elems;
    };
    __bf16 *h0h, *h0l, *a1h, *a1l, *d1h, *d1l, *d2h, *d2l;
    aplane(64,  chunk, h0h, h0l);
    aplane(32,  chunk, a1h, a1l);
    aplane(128, chunk, d1h, d1l);   // also reused for r1
    aplane(128, chunk, d2h, d2l);
    __bf16 *r1h = d1h, *r1l = d1l;

    // ---- weight prep (tiny) ----
    auto pg = [](int tot) { return dim3((tot + 255) / 256); };
    prep_w_k<64, 32, 7>  <<<pg(2*7*2*2*64),  dim3(256), 0, stream>>>(Wa1, wa1f);
    prep_w_k<32, 64, 7>  <<<pg(1*7*4*2*64),  dim3(256), 0, stream>>>(Wa2, wa2f);
    prep_w_k<64, 128, 3> <<<pg(2*3*8*2*64),  dim3(256), 0, stream>>>(Wd1, wd1f);
    prep_w_k<128, 128, 3><<<pg(4*3*8*2*64),  dim3(256), 0, stream>>>(Wd2, wd2f);
    prep_w_k<128, 128, 3><<<pg(4*3*8*2*64),  dim3(256), 0, stream>>>(Wr1, wr1f);
    prep_w_k<128, 128, 3><<<pg(4*3*8*2*64),  dim3(256), 0, stream>>>(Wr2, wr2f);

    hipMemsetAsync(gbuf, 0, (size_t)B * 128 * sizeof(float), stream);
    hipMemsetAsync(zpage, 0, 256, stream);

    const dim3 blk(256);
    for (int sft = 0; sft < B; sft += chunk) {
        const int c = (chunk < B - sft) ? chunk : (B - sft);
        const dim3 cg(L_LEN / 128, 1, c);
        conv1_split_k<<<dim3(64, c), dim3(256), 0, stream>>>(x + (size_t)sft * L_LEN, W1, b1, bn1, h0h, h0l);
        conv_mfma_k<64, 32, 7, 1, 0><<<cg, blk, 0, stream>>>(h0h, h0l, wa1f, ba1, bna1, nullptr, nullptr, a1h, a1l, nullptr, zpage);
        conv_mfma_k<32, 64, 7, 1, 1><<<cg, blk, 0, stream>>>(a1h, a1l, wa2f, ba2, bna2, h0h, h0l, h0h, h0l, nullptr, zpage);
        conv_mfma_k<64, 128, 3, 2, 0><<<cg, blk, 0, stream>>>(h0h, h0l, wd1f, bdd1, bnd1, nullptr, nullptr, d1h, d1l, nullptr, zpage);
        conv_mfma_k<128, 128, 3, 4, 0><<<cg, blk, 0, stream>>>(d1h, d1l, wd2f, bdd2, bnd2, nullptr, nullptr, d2h, d2l, nullptr, zpage);
        conv_mfma_k<128, 128, 3, 1, 0><<<cg, blk, 0, stream>>>(d2h, d2l, wr1f, br1, bnr1, nullptr, nullptr, r1h, r1l, nullptr, zpage);
        conv_mfma_k<128, 128, 3, 1, 3><<<cg, blk, 0, stream>>>(r1h, r1l, wr2f, br2, bnr2, d2h, d2l, nullptr, nullptr, gbuf + (size_t)sft * 128, zpage);
    }

    quantum_k<<<dim3((B + 127) / 128), dim3(128), 0, stream>>>(gbuf, Wfm, bfm, qw, qbuf, B);
    head_k<<<dim3(B), dim3(64), 0, stream>>>(qbuf, Wf1, bf1, bnf1, Wf2, bf2, bnf2, Wf3, bf3, (float*)d_out);
}

// Round 6
// 712.299 us; speedup vs baseline: 16.6313x; 1.5863x over previous
//
#include <hip/hip_runtime.h>
#include <math.h>

#define L_LEN 4096
#define DEV __device__ __forceinline__

typedef __attribute__((ext_vector_type(8))) _Float16 f16x8;
typedef __attribute__((ext_vector_type(4))) float   f32x4;

DEV float silu_f(float x) { return x / (1.f + expf(-x)); }
DEV float sigm_f(float x) { return 1.f / (1.f + expf(-x)); }

DEV void gload16(const void* g, void* l) {
    __builtin_amdgcn_global_load_lds(
        (const __attribute__((address_space(1))) void*)g,
        (__attribute__((address_space(3))) void*)l, 16, 0, 0);
}

// ============================================================================
// conv1: CIN=1, K=5, pad=2 (fp32 direct; writes fp16 channels-last)
// ============================================================================
__global__ __launch_bounds__(256) void conv1_k(
    const float* __restrict__ x, const float* __restrict__ W,
    const float* __restrict__ bias, const float* __restrict__ bnp,
    _Float16* __restrict__ out)
{
    __shared__ float sw[64 * 5];
    __shared__ float ssc[64], ssh[64];
    const int tid = threadIdx.x;
    if (tid < 64) {
        float g = bnp[tid], be = bnp[64 + tid], mn = bnp[128 + tid], vr = bnp[192 + tid];
        float sc = g * rsqrtf(vr + 1e-5f);
        ssc[tid] = sc;
        ssh[tid] = fmaf(bias[tid] - mn, sc, be);
    }
    for (int i = tid; i < 320; i += 256) sw[i] = W[i];
    __syncthreads();

    const int b = blockIdx.y;
    const int l = blockIdx.x * 64 + (tid >> 2);
    const int cq = (tid & 3) * 16;

    float win[5];
#pragma unroll
    for (int k = 0; k < 5; ++k) {
        int ix = l + k - 2;
        win[k] = (ix >= 0 && ix < L_LEN) ? x[(size_t)b * L_LEN + ix] : 0.f;
    }
    __align__(16) _Float16 vv[16];
#pragma unroll
    for (int j = 0; j < 16; ++j) {
        const int co = cq + j;
        float z = 0.f;
#pragma unroll
        for (int k = 0; k < 5; ++k) z = fmaf(sw[co * 5 + k], win[k], z);
        z = fmaf(z, ssc[co], ssh[co]);
        vv[j] = (_Float16)silu_f(z);
    }
    const size_t o = ((size_t)b * L_LEN + l) * 64 + cq;
    *(int4*)(out + o)     = *(const int4*)(vv);
    *(int4*)(out + o + 8) = *(const int4*)(vv + 8);
}

// ============================================================================
// weight prep -> fragment-order fp16 split: [s][t][n][pl][lane][8]
//   co = n*16 + (lane&15), ci = s*32 + (lane>>4)*8 + j; pl0=hi, pl1=lo
// ============================================================================
template <int CIN, int COUT, int K>
__global__ void prep_w_k(const float* __restrict__ W, _Float16* __restrict__ wf)
{
    constexpr int NTILE = COUT / 16;
    const int i = blockIdx.x * 256 + threadIdx.x;
    const int total = (CIN / 32) * K * NTILE * 2 * 64;
    if (i >= total) return;
    const int lane = i & 63;
    int r = i >> 6;
    const int pl = r & 1;  r >>= 1;
    const int n  = r % NTILE; r /= NTILE;
    const int t  = r % K;
    const int s  = r / K;

    const int co  = n * 16 + (lane & 15);
    const int cib = s * 32 + (lane >> 4) * 8;
    __align__(16) _Float16 v8[8];
#pragma unroll
    for (int j = 0; j < 8; ++j) {
        const float v = W[((size_t)co * CIN + cib + j) * K + t];
        const _Float16 h = (_Float16)v;
        v8[j] = pl ? (_Float16)(v - (float)h) : h;
    }
    *(int4*)(wf + (size_t)i * 8) = *(const int4*)v8;
}

// ============================================================================
// MFMA fp16 implicit-GEMM conv (weights split hi/lo; activations fp16).
// Block: 256 thr = 4 waves (2 wl x 2 wc); tile = 128 l x COUT.
// A in LDS (double-buffered per ci-slice, 80B rows, lane-linear staging).
// B per-phase from global/L2 into explicit register double-buffer brbuf[2].
// Epilogue (MODE 0/1): z -> LDS [128][COUT] fp16 transpose -> coalesced
// 1KB/wave stores (and coalesced gate loads). MODE 3: direct pooled reduce.
// ============================================================================
template <int CIN, int COUT, int K, int DIL, int MODE>
__launch_bounds__(256, 2) __global__ void conv_mfma_k(
    const _Float16* __restrict__ in, const _Float16* __restrict__ wf,
    const float* __restrict__ bias,  const float* __restrict__ bnp,
    const _Float16* __restrict__ aux, _Float16* __restrict__ out,
    float* __restrict__ gsum, const float* __restrict__ zpage)
{
    constexpr int SL    = CIN / 32;
    constexpr int P     = SL * K;
    constexpr int PADR  = ((K - 1) / 2) * DIL;
    constexpr int LWIN  = 128 + (K - 1) * DIL;
    constexpr int NT    = COUT / 32;
    constexpr int NTILE = COUT / 16;
    constexpr int CH_IN = LWIN * 5;           // 16B chunks per slice (slot4 = pad)
    constexpr int BUFB  = LWIN * 80;          // bytes per staging buffer
    constexpr int EPIB  = 128 * COUT * 2;     // epilogue transpose tile bytes
    constexpr int SMEMB = (2 * BUFB > EPIB) ? 2 * BUFB : EPIB;

    __shared__ __align__(16) char smem[SMEMB];

    const int tid   = threadIdx.x;
    const int lane  = tid & 63;
    const int w     = tid >> 6;
    const int wl    = w >> 1;                 // 0..1 : l half (64 rows)
    const int wc    = w & 1;                  // 0..1 : co half
    const int b     = blockIdx.z;
    const int l0    = blockIdx.x * 128;
    const int lan15 = lane & 15;
    const int kgB   = (lane >> 4) * 16;

    const size_t bL = (size_t)b * L_LEN;

    auto stage_in = [&](int s, int buf) {
        const int ci0 = s * 32;
        char* dst = smem + buf * BUFB;
        for (int c = tid; c < CH_IN; c += 256) {
            const int row  = c / 5;
            const int slot = c - row * 5;
            const int gl   = l0 - PADR + row;
            const bool ok  = (slot < 4) & (gl >= 0) & (gl < L_LEN);
            const _Float16* s0 = in + ((bL + gl) * CIN + ci0 + slot * 8);
            const void* src = ok ? (const void*)s0 : (const void*)zpage;
            gload16(src, dst + (size_t)c * 16);
        }
    };

    auto loadB = [&](int p, f16x8 (&dst)[2 * NT]) {
        const _Float16* bbase = wf + (size_t)p * (NTILE * 1024);
#pragma unroll
        for (int nt = 0; nt < NT; ++nt) {
            const int ntg = wc * NT + nt;
            dst[nt * 2 + 0] = *(const f16x8*)(bbase + (ntg * 2 + 0) * 512 + lane * 8);
            dst[nt * 2 + 1] = *(const f16x8*)(bbase + (ntg * 2 + 1) * 512 + lane * 8);
        }
    };

    f32x4 acc[4][NT];
#pragma unroll
    for (int mt = 0; mt < 4; ++mt)
#pragma unroll
        for (int nt = 0; nt < NT; ++nt) acc[mt][nt] = (f32x4){0.f, 0.f, 0.f, 0.f};

    f16x8 brbuf[2][2 * NT];

    // ---- prologue ----
    stage_in(0, 0);
    loadB(0, brbuf[0]);
    asm volatile("s_waitcnt vmcnt(0)" ::: "memory");
    __builtin_amdgcn_sched_barrier(0);
    __syncthreads();

    // ---- fully static phase loop ----
#pragma unroll
    for (int pp = 0; pp < P; ++pp) {
        const int ss = pp / K;
        const int tt = pp % K;

        if (tt == 0 && ss + 1 < SL) stage_in(ss + 1, (ss + 1) & 1);
        if (pp + 1 < P) loadB(pp + 1, brbuf[(pp + 1) & 1]);

        const char* ibase = smem + (ss & 1) * BUFB;
#pragma unroll
        for (int mt = 0; mt < 4; ++mt) {
            const int row = wl * 64 + mt * 16 + lan15 + tt * DIL;
            const f16x8 a = *(const f16x8*)(ibase + row * 80 + kgB);
#pragma unroll
            for (int nt = 0; nt < NT; ++nt) {
                acc[mt][nt] = __builtin_amdgcn_mfma_f32_16x16x32_f16(a, brbuf[pp & 1][nt * 2 + 0], acc[mt][nt], 0, 0, 0);
                acc[mt][nt] = __builtin_amdgcn_mfma_f32_16x16x32_f16(a, brbuf[pp & 1][nt * 2 + 1], acc[mt][nt], 0, 0, 0);
            }
        }

        if (tt == K - 1 && ss + 1 < SL) {
            asm volatile("s_waitcnt vmcnt(0)" ::: "memory");
            __builtin_amdgcn_sched_barrier(0);
            __syncthreads();
        }
    }

    // ---------------- epilogue ----------------
    if constexpr (MODE == 3) {
#pragma unroll
        for (int nt = 0; nt < NT; ++nt) {
            const int co = (wc * NT + nt) * 16 + lan15;
            const float g = bnp[co], be = bnp[COUT + co], mn = bnp[2 * COUT + co], vr = bnp[3 * COUT + co];
            const float sc = g * rsqrtf(vr + 1e-5f);
            const float sh = fmaf(bias[co] - mn, sc, be);
            float ps = 0.f;
#pragma unroll
            for (int mt = 0; mt < 4; ++mt) {
#pragma unroll
                for (int r = 0; r < 4; ++r) {
                    const int l = l0 + wl * 64 + mt * 16 + (lane >> 4) * 4 + r;
                    const size_t gidx = (bL + l) * COUT + co;
                    const float z = fmaf(acc[mt][nt][r], sc, sh);
                    ps += silu_f(z + (float)aux[gidx]);
                }
            }
            ps += __shfl_down(ps, 32, 64);
            ps += __shfl_down(ps, 16, 64);
            if ((lane >> 4) == 0) atomicAdd(&gsum[b * COUT + co], ps);
        }
    } else {
        __syncthreads();   // all staging reads done before smem reuse
        _Float16* zl = (_Float16*)smem;
#pragma unroll
        for (int nt = 0; nt < NT; ++nt) {
            const int co = (wc * NT + nt) * 16 + lan15;
            const float g = bnp[co], be = bnp[COUT + co], mn = bnp[2 * COUT + co], vr = bnp[3 * COUT + co];
            const float sc = g * rsqrtf(vr + 1e-5f);
            const float sh = fmaf(bias[co] - mn, sc, be);
#pragma unroll
            for (int mt = 0; mt < 4; ++mt) {
#pragma unroll
                for (int r = 0; r < 4; ++r) {
                    const int l_loc = wl * 64 + mt * 16 + (lane >> 4) * 4 + r;
                    zl[l_loc * COUT + co] = (_Float16)fmaf(acc[mt][nt][r], sc, sh);
                }
            }
        }
        __syncthreads();

        // coalesced sweep: 1KB contiguous per wave-store
        constexpr int CO8 = COUT / 8;
        constexpr int LG  = (CO8 == 16) ? 4 : (CO8 == 8) ? 3 : 2;
        constexpr int RPI = 64 / CO8;          // rows per instruction
        const int co = (lane & (CO8 - 1)) * 8;
#pragma unroll
        for (int s2 = 0; s2 < CO8 / 2; ++s2) {
            const int l = w * 32 + s2 * RPI + (lane >> LG);
            const int4 zi = *(const int4*)&zl[l * COUT + co];
            _Float16 z8[8];
            *(int4*)z8 = zi;
            const size_t gidx = (bL + l0 + l) * COUT + co;
            __align__(16) _Float16 o8[8];
            if constexpr (MODE == 0) {
#pragma unroll
                for (int j = 0; j < 8; ++j) o8[j] = (_Float16)silu_f((float)z8[j]);
            } else {
                const int4 gi = *(const int4*)(aux + gidx);
                _Float16 g8[8];
                *(int4*)g8 = gi;
#pragma unroll
                for (int j = 0; j < 8; ++j) o8[j] = (_Float16)((float)g8[j] * sigm_f((float)z8[j]));
            }
            *(int4*)(out + gidx) = *(const int4*)o8;
        }
    }
}

// ============================================================================
// 4-qubit statevector circuit, one thread per batch row
// ============================================================================
template <int BW> DEV void g_ry(float (&re)[16], float (&im)[16], float t) {
    float s, c; sincosf(0.5f * t, &s, &c);
#pragma unroll
    for (int i = 0; i < 16; ++i)
        if (!(i & BW)) {
            const int j = i | BW;
            float r0 = re[i], q0 = im[i], r1 = re[j], q1 = im[j];
            re[i] = c * r0 - s * r1; im[i] = c * q0 - s * q1;
            re[j] = s * r0 + c * r1; im[j] = s * q0 + c * q1;
        }
}
template <int BW> DEV void g_rz(float (&re)[16], float (&im)[16], float t) {
    float s, c; sincosf(0.5f * t, &s, &c);
#pragma unroll
    for (int i = 0; i < 16; ++i) {
        float r = re[i], q = im[i];
        if (i & BW) { re[i] = r * c - q * s; im[i] = q * c + r * s; }
        else        { re[i] = r * c + q * s; im[i] = q * c - r * s; }
    }
}
template <int BC, int BT> DEV void g_cnot(float (&re)[16], float (&im)[16]) {
#pragma unroll
    for (int i = 0; i < 16; ++i)
        if ((i & BC) && !(i & BT)) {
            const int j = i | BT;
            float r = re[i]; re[i] = re[j]; re[j] = r;
            float q = im[i]; im[i] = im[j]; im[j] = q;
        }
}

__global__ void quantum_k(const float* __restrict__ gsum, const float* __restrict__ Wfm,
                          const float* __restrict__ bfm, const float* __restrict__ qw,
                          float* __restrict__ q, int B)
{
    const int b = blockIdx.x * blockDim.x + threadIdx.x;
    if (b >= B) return;

    float qin[4];
#pragma unroll
    for (int j = 0; j < 4; ++j) qin[j] = bfm[j];
    const float inv = 1.f / (float)L_LEN;
    for (int c = 0; c < 128; ++c) {
        const float gv = gsum[b * 128 + c] * inv;
#pragma unroll
        for (int j = 0; j < 4; ++j) qin[j] = fmaf(gv, Wfm[j * 128 + c], qin[j]);
    }

    float re[16], im[16];
#pragma unroll
    for (int i = 0; i < 16; ++i) { re[i] = 0.f; im[i] = 0.f; }
    re[0] = 1.f;

    g_ry<8>(re, im, qin[0]); g_ry<4>(re, im, qin[1]); g_ry<2>(re, im, qin[2]); g_ry<1>(re, im, qin[3]);
    g_rz<8>(re, im, qw[0]);  g_ry<8>(re, im, qw[1]);
    g_rz<4>(re, im, qw[2]);  g_ry<4>(re, im, qw[3]);
    g_rz<2>(re, im, qw[4]);  g_ry<2>(re, im, qw[5]);
    g_rz<1>(re, im, qw[6]);  g_ry<1>(re, im, qw[7]);
    g_cnot<8, 4>(re, im); g_cnot<4, 2>(re, im); g_cnot<2, 1>(re, im);
    g_rz<8>(re, im, qw[8]);  g_ry<8>(re, im, qw[9]);
    g_rz<4>(re, im, qw[10]); g_ry<4>(re, im, qw[11]);
    g_rz<2>(re, im, qw[12]); g_ry<2>(re, im, qw[13]);
    g_rz<1>(re, im, qw[14]); g_ry<1>(re, im, qw[15]);

    float pr[16];
#pragma unroll
    for (int i = 0; i < 16; ++i) pr[i] = re[i] * re[i] + im[i] * im[i];
#pragma unroll
    for (int w = 0; w < 4; ++w) {
        const int bw = 8 >> w;
        float e = 0.f;
#pragma unroll
        for (int i = 0; i < 16; ++i) e += (i & bw) ? -pr[i] : pr[i];
        q[b * 4 + w] = e;
    }
}

// ============================================================================
// FC head: 4 -> 64 -> 32 -> 1
// ============================================================================
__global__ void head_k(const float* __restrict__ q,
                       const float* __restrict__ Wf1, const float* __restrict__ bf1, const float* __restrict__ bnf1,
                       const float* __restrict__ Wf2, const float* __restrict__ bf2, const float* __restrict__ bnf2,
                       const float* __restrict__ Wf3, const float* __restrict__ bf3,
                       float* __restrict__ out)
{
    const int b = blockIdx.x, t = threadIdx.x;
    __shared__ float qs[4], x1[64], x2[32];
    if (t < 4) qs[t] = q[b * 4 + t];
    __syncthreads();
    {
        float a = bf1[t];
#pragma unroll
        for (int k = 0; k < 4; ++k) a = fmaf(qs[k], Wf1[t * 4 + k], a);
        const float sc = bnf1[t] / sqrtf(bnf1[192 + t] + 1e-5f);
        const float z  = (a - bnf1[128 + t]) * sc + bnf1[64 + t];
        x1[t] = silu_f(z);
    }
    __syncthreads();
    if (t < 32) {
        float a = bf2[t];
        for (int k = 0; k < 64; ++k) a = fmaf(x1[k], Wf2[t * 64 + k], a);
        const float sc = bnf2[t] / sqrtf(bnf2[96 + t] + 1e-5f);
        const float z  = (a - bnf2[64 + t]) * sc + bnf2[32 + t];
        x2[t] = silu_f(z);
    }
    __syncthreads();
    if (t == 0) {
        float a = bf3[0];
        for (int k = 0; k < 32; ++k) a = fmaf(x2[k], Wf3[k], a);
        out[b] = a;
    }
}

// ============================================================================
extern "C" void kernel_launch(void* const* d_in, const int* in_sizes, int n_in,
                              void* d_out, int out_size, void* d_ws, size_t ws_size,
                              hipStream_t stream)
{
    (void)n_in; (void)out_size;
    const float* x    = (const float*)d_in[0];
    const float* W1   = (const float*)d_in[1];
    const float* b1   = (const float*)d_in[2];
    const float* bn1  = (const float*)d_in[3];
    const float* Wa1  = (const float*)d_in[4];
    const float* ba1  = (const float*)d_in[5];
    const float* bna1 = (const float*)d_in[6];
    const float* Wa2  = (const float*)d_in[7];
    const float* ba2  = (const float*)d_in[8];
    const float* bna2 = (const float*)d_in[9];
    const float* Wd1  = (const float*)d_in[10];
    const float* bdd1 = (const float*)d_in[11];
    const float* bnd1 = (const float*)d_in[12];
    const float* Wd2  = (const float*)d_in[13];
    const float* bdd2 = (const float*)d_in[14];
    const float* bnd2 = (const float*)d_in[15];
    const float* Wr1  = (const float*)d_in[16];
    const float* br1  = (const float*)d_in[17];
    const float* bnr1 = (const float*)d_in[18];
    const float* Wr2  = (const float*)d_in[19];
    const float* br2  = (const float*)d_in[20];
    const float* bnr2 = (const float*)d_in[21];
    const float* Wfm  = (const float*)d_in[22];
    const float* bfm  = (const float*)d_in[23];
    const float* qw   = (const float*)d_in[24];
    const float* Wf1  = (const float*)d_in[25];
    const float* bf1  = (const float*)d_in[26];
    const float* bnf1 = (const float*)d_in[27];
    const float* Wf2  = (const float*)d_in[28];
    const float* bf2  = (const float*)d_in[29];
    const float* bnf2 = (const float*)d_in[30];
    const float* Wf3  = (const float*)d_in[31];
    const float* bf3  = (const float*)d_in[32];

    const int B = in_sizes[0] / L_LEN;  // 128

    // ---- workspace carve (256B aligned bump allocator) ----
    char* base = (char*)d_ws;
    size_t off = 0;
    auto alloc = [&](size_t bytes) -> char* {
        off = (off + 255) & ~(size_t)255;
        char* p = base + off;
        off += bytes;
        return p;
    };

    float* gbuf  = (float*)alloc((size_t)B * 128 * 4);
    float* qbuf  = (float*)alloc((size_t)B * 4 * 4);
    float* zpage = (float*)alloc(256);

    auto wfrag = [&](int cin, int cout, int k) -> _Float16* {
        return (_Float16*)alloc((size_t)k * cout * cin * 2 * 2);
    };
    _Float16* wa1f = wfrag(64, 32, 7);
    _Float16* wa2f = wfrag(32, 64, 7);
    _Float16* wd1f = wfrag(64, 128, 3);
    _Float16* wd2f = wfrag(128, 128, 3);
    _Float16* wr1f = wfrag(128, 128, 3);
    _Float16* wr2f = wfrag(128, 128, 3);

    const size_t fixed = (off + 255) & ~(size_t)255;
    const size_t PS = (size_t)2 * L_LEN * (64 + 32 + 128 + 128);  // fp16 single-plane
    size_t avail = (ws_size > fixed + 4096) ? ws_size - fixed - 4096 : 0;
    int chunk = B;
    while (chunk > 1 && (size_t)chunk * PS > avail) chunk >>= 1;

    auto aplane = [&](int C, int c) -> _Float16* {
        return (_Float16*)alloc((size_t)c * L_LEN * C * 2);
    };
    _Float16* h0 = aplane(64,  chunk);
    _Float16* a1 = aplane(32,  chunk);
    _Float16* d1 = aplane(128, chunk);   // also reused for r1
    _Float16* d2 = aplane(128, chunk);
    _Float16* r1 = d1;

    // ---- weight prep (tiny) ----
    auto pg = [](int tot) { return dim3((tot + 255) / 256); };
    prep_w_k<64, 32, 7>  <<<pg(2*7*2*2*64),  dim3(256), 0, stream>>>(Wa1, wa1f);
    prep_w_k<32, 64, 7>  <<<pg(1*7*4*2*64),  dim3(256), 0, stream>>>(Wa2, wa2f);
    prep_w_k<64, 128, 3> <<<pg(2*3*8*2*64),  dim3(256), 0, stream>>>(Wd1, wd1f);
    prep_w_k<128, 128, 3><<<pg(4*3*8*2*64),  dim3(256), 0, stream>>>(Wd2, wd2f);
    prep_w_k<128, 128, 3><<<pg(4*3*8*2*64),  dim3(256), 0, stream>>>(Wr1, wr1f);
    prep_w_k<128, 128, 3><<<pg(4*3*8*2*64),  dim3(256), 0, stream>>>(Wr2, wr2f);

    hipMemsetAsync(gbuf, 0, (size_t)B * 128 * sizeof(float), stream);
    hipMemsetAsync(zpage, 0, 256, stream);

    const dim3 blk(256);
    for (int sft = 0; sft < B; sft += chunk) {
        const int c = (chunk < B - sft) ? chunk : (B - sft);
        const dim3 cg(L_LEN / 128, 1, c);
        conv1_k<<<dim3(64, c), dim3(256), 0, stream>>>(x + (size_t)sft * L_LEN, W1, b1, bn1, h0);
        conv_mfma_k<64, 32, 7, 1, 0><<<cg, blk, 0, stream>>>(h0, wa1f, ba1, bna1, nullptr, a1, nullptr, zpage);
        conv_mfma_k<32, 64, 7, 1, 1><<<cg, blk, 0, stream>>>(a1, wa2f, ba2, bna2, h0, h0, nullptr, zpage);
        conv_mfma_k<64, 128, 3, 2, 0><<<cg, blk, 0, stream>>>(h0, wd1f, bdd1, bnd1, nullptr, d1, nullptr, zpage);
        conv_mfma_k<128, 128, 3, 4, 0><<<cg, blk, 0, stream>>>(d1, wd2f, bdd2, bnd2, nullptr, d2, nullptr, zpage);
        conv_mfma_k<128, 128, 3, 1, 0><<<cg, blk, 0, stream>>>(d2, wr1f, br1, bnr1, nullptr, r1, nullptr, zpage);
        conv_mfma_k<128, 128, 3, 1, 3><<<cg, blk, 0, stream>>>(r1, wr2f, br2, bnr2, d2, nullptr, gbuf + (size_t)sft * 128, zpage);
    }

    quantum_k<<<dim3((B + 127) / 128), dim3(128), 0, stream>>>(gbuf, Wfm, bfm, qw, qbuf, B);
    head_k<<<dim3(B), dim3(64), 0, stream>>>(qbuf, Wf1, bf1, bnf1, Wf2, bf2, bnf2, Wf3, bf3, (float*)d_out);
}